// Round 1
// baseline (618.475 us; speedup 1.0000x reference)
//
#include <hip/hip_runtime.h>
#include <cmath>

#define TT 16
#define BB 16
#define NN 1024
#define EE 16384
#define FIN 128
#define MIDC 16
#define HH 256
#define KK 820
#define HS 20           // hbuf row stride in floats (80 B, 16 B aligned for ds_read_b128)

// ---- LDS float-slot layout for k_graph ----
#define OFF_HBUF   0
#define N_HBUF     (NN*HS)                    // 20480
#define OFF_CSR    (OFF_HBUF + N_HBUF)        // ushort[EE] -> 8192 float slots (reused as partials[16][256] at the end)
#define N_CSR      (EE/2)
#define OFF_HEAD   (OFF_CSR + N_CSR)          // int[NN+1]
#define OFF_CUR    (OFF_HEAD + NN + 1)        // int[NN]
#define OFF_SCANA  (OFF_CUR + NN)             // int[NN]
#define OFF_DINV   (OFF_SCANA + NN)           // float[NN] (aliases scanB during the prefix scan)
#define OFF_UB     (OFF_DINV + NN)            // uint[NN] kept mask
#define OFF_HIST   (OFF_UB + NN)              // int[256]
#define OFF_S      (OFF_HIST + 256)           // int[256] suffix sums
#define OFF_WCNT   (OFF_S + 256)              // int[16]
#define OFF_CTRL   (OFF_WCNT + 16)            // int[8]
#define SM_FLOATS  (OFF_CTRL + 8)
#define SM_BYTES   (SM_FLOATS * 4)            // ~137.3 KB

// ---------------------------------------------------------------------------
// K1: one block per graph, 1024 threads (= N nodes). conv1 -> CSR build ->
// gather conv1 -> gather SAG -> radix top-K -> gate -> gather conv2 ->
// 16x256 matmul + relu + mean pool.  No float atomics anywhere.
// (UNCHANGED this round — audited clean; this round attacks the LSTM chain)
// ---------------------------------------------------------------------------
__global__ __launch_bounds__(1024) void k_graph(
    const float* __restrict__ x, const int* __restrict__ ei,
    const float* __restrict__ W1, const float* __restrict__ b1,
    const float* __restrict__ Wl, const float* __restrict__ Wr,
    const float* __restrict__ bsag, const float* __restrict__ W2,
    const float* __restrict__ b2, float* __restrict__ emb)
{
  extern __shared__ __align__(16) float sm[];
  float*          hbuf  = sm + OFF_HBUF;
  float4*         hb4   = (float4*)hbuf;
  unsigned short* csr   = (unsigned short*)(sm + OFF_CSR);
  int*            head  = (int*)(sm + OFF_HEAD);
  int*            cur   = (int*)(sm + OFF_CUR);
  int*            scanA = (int*)(sm + OFF_SCANA);
  int*            scanB = (int*)(sm + OFF_DINV);     // alias, freed before dinv use
  float*          dinvb = sm + OFF_DINV;
  unsigned*       ubv   = (unsigned*)(sm + OFF_UB);
  int*            hist  = (int*)(sm + OFF_HIST);
  int*            S     = (int*)(sm + OFF_S);
  int*            wcnt  = (int*)(sm + OFF_WCNT);
  int*            ctrl  = (int*)(sm + OFF_CTRL);

  const int g   = blockIdx.x;
  const int tid = threadIdx.x;
  const float* xg   = x  + (size_t)g * (NN*FIN);
  const int*   srcp = ei + (size_t)g * (2*EE);
  const int*   dstp = srcp + EE;

  cur[tid] = 0;

  // ---- conv1 matmul: hown = x_row @ W1 (W1 via wave-uniform s_loads) ----
  float hown[MIDC];
  {
    const float4* xr = (const float4*)(xg + (size_t)tid * FIN);
#pragma unroll
    for (int c = 0; c < MIDC; ++c) hown[c] = 0.0f;
    for (int k4 = 0; k4 < FIN/4; ++k4) {
      float4 v = xr[k4];
      const float* w0 = W1 + (k4*4 + 0)*MIDC;
      const float* w1 = W1 + (k4*4 + 1)*MIDC;
      const float* w2 = W1 + (k4*4 + 2)*MIDC;
      const float* w3 = W1 + (k4*4 + 3)*MIDC;
#pragma unroll
      for (int c = 0; c < MIDC; ++c)
        hown[c] += v.x*w0[c] + v.y*w1[c] + v.z*w2[c] + v.w*w3[c];
    }
    hb4[tid*5+0] = make_float4(hown[0],  hown[1],  hown[2],  hown[3]);
    hb4[tid*5+1] = make_float4(hown[4],  hown[5],  hown[6],  hown[7]);
    hb4[tid*5+2] = make_float4(hown[8],  hown[9],  hown[10], hown[11]);
    hb4[tid*5+3] = make_float4(hown[12], hown[13], hown[14], hown[15]);
  }
  __syncthreads();

  // ---- degree count (int atomics, native) ----
  for (int e = tid; e < EE; e += 1024) atomicAdd(&cur[dstp[e]], 1);
  __syncthreads();

  // ---- exclusive prefix scan (Hillis-Steele, ping-pong) ----
  {
    int v = cur[tid];
    scanA[tid] = v;
    __syncthreads();
    int* s_ = scanA; int* d_ = scanB;
    for (int off = 1; off < NN; off <<= 1) {
      int t = s_[tid];
      if (tid >= off) t += s_[tid - off];
      d_[tid] = t;
      __syncthreads();
      int* tmp = s_; s_ = d_; d_ = tmp;
    }
    int inc = s_[tid];
    int ex  = inc - v;
    __syncthreads();                 // all scan reads done before dinvb overwrite
    head[tid] = ex;
    cur[tid]  = ex;
    if (tid == 0) head[NN] = EE;
    dinvb[tid] = rsqrtf((float)(v + 1));
  }
  __syncthreads();

  // ---- CSR fill (src ids as ushort) ----
  for (int e = tid; e < EE; e += 1024) {
    int s = srcp[e], d = dstp[e];
    int pos = atomicAdd(&cur[d], 1);
    csr[pos] = (unsigned short)s;
  }
  __syncthreads();

  const int beg = head[tid], end = head[tid+1];

  // ---- gather conv1: acc = sum_s dinv_s * h_s ----
  float h1own[MIDC];
  {
    float accv[MIDC];
#pragma unroll
    for (int c = 0; c < MIDC; ++c) accv[c] = 0.0f;
    for (int p = beg; p < end; ++p) {
      int s = csr[p];
      float ds_ = dinvb[s];
      float4 a0 = hb4[s*5+0], a1 = hb4[s*5+1], a2 = hb4[s*5+2], a3 = hb4[s*5+3];
      accv[0]  += a0.x*ds_; accv[1]  += a0.y*ds_; accv[2]  += a0.z*ds_; accv[3]  += a0.w*ds_;
      accv[4]  += a1.x*ds_; accv[5]  += a1.y*ds_; accv[6]  += a1.z*ds_; accv[7]  += a1.w*ds_;
      accv[8]  += a2.x*ds_; accv[9]  += a2.y*ds_; accv[10] += a2.z*ds_; accv[11] += a2.w*ds_;
      accv[12] += a3.x*ds_; accv[13] += a3.y*ds_; accv[14] += a3.z*ds_; accv[15] += a3.w*ds_;
    }
    float di = dinvb[tid];
#pragma unroll
    for (int c = 0; c < MIDC; ++c)
      h1own[c] = fmaxf(di*accv[c] + hown[c]*di*di + b1[c], 0.0f);
  }
  __syncthreads();
  hb4[tid*5+0] = make_float4(h1own[0],  h1own[1],  h1own[2],  h1own[3]);
  hb4[tid*5+1] = make_float4(h1own[4],  h1own[5],  h1own[6],  h1own[7]);
  hb4[tid*5+2] = make_float4(h1own[8],  h1own[9],  h1own[10], h1own[11]);
  hb4[tid*5+3] = make_float4(h1own[12], h1own[13], h1own[14], h1own[15]);
  __syncthreads();

  // ---- gather SAG: agg = sum_s h1_s ; score ----
  float score;
  unsigned myu;
  {
    float aggv[MIDC];
#pragma unroll
    for (int c = 0; c < MIDC; ++c) aggv[c] = 0.0f;
    for (int p = beg; p < end; ++p) {
      int s = csr[p];
      float4 a0 = hb4[s*5+0], a1 = hb4[s*5+1], a2 = hb4[s*5+2], a3 = hb4[s*5+3];
      aggv[0]  += a0.x; aggv[1]  += a0.y; aggv[2]  += a0.z; aggv[3]  += a0.w;
      aggv[4]  += a1.x; aggv[5]  += a1.y; aggv[6]  += a1.z; aggv[7]  += a1.w;
      aggv[8]  += a2.x; aggv[9]  += a2.y; aggv[10] += a2.z; aggv[11] += a2.w;
      aggv[12] += a3.x; aggv[13] += a3.y; aggv[14] += a3.z; aggv[15] += a3.w;
    }
    score = bsag[0];
#pragma unroll
    for (int c = 0; c < MIDC; ++c) score += aggv[c]*Wl[c] + h1own[c]*Wr[c];
    unsigned ubits = __float_as_uint(score);
    myu = (ubits & 0x80000000u) ? ~ubits : (ubits | 0x80000000u);
  }

  // ---- radix select K-th largest key (parallel suffix scan per round) ----
  int remK = KK;
  unsigned pref = 0;
  for (int byte = 3; byte >= 0; --byte) {
    if (tid < 256) hist[tid] = 0;
    __syncthreads();
    const int sh = byte * 8;
    const unsigned hi_mask = (byte == 3) ? 0u : (0xFFFFFFFFu << (sh + 8));
    if ((myu & hi_mask) == pref) atomicAdd(&hist[(myu >> sh) & 255u], 1);
    __syncthreads();
    if (tid < 64) {
      int h0 = hist[tid*4+0], h1_ = hist[tid*4+1], h2_ = hist[tid*4+2], h3_ = hist[tid*4+3];
      int s3 = h3_, s2 = h2_ + s3, s1 = h1_ + s2, s0 = h0 + s1;
      int run = s0;
#pragma unroll
      for (int off = 1; off < 64; off <<= 1) {
        int o = __shfl_down(run, off);
        if (tid + off < 64) run += o;
      }
      int above = run - s0;
      S[tid*4+0] = above + s0;
      S[tid*4+1] = above + s1;
      S[tid*4+2] = above + s2;
      S[tid*4+3] = above + s3;
    }
    __syncthreads();
    if (tid < 256) {
      int Sv = S[tid];
      int Sn = (tid < 255) ? S[tid+1] : 0;
      if (Sv >= remK && Sn < remK) { ctrl[0] = remK - Sn; ctrl[1] = tid; }
    }
    __syncthreads();
    remK  = ctrl[0];
    pref |= ((unsigned)ctrl[1]) << sh;
    __syncthreads();
  }
  const unsigned vstar = pref;
  const int need = remK;

  // ---- kept mask: ties broken by lowest index (ballot-based count) ----
  {
    const int wid = tid >> 6, lane = tid & 63;
    bool eq = (myu == vstar);
    unsigned long long m = __ballot(eq);
    if (lane == 0) wcnt[wid] = __popcll(m);
    __syncthreads();
    int before = (lane == 0) ? 0 : __popcll(m & ((~0ull) >> (64 - lane)));
    for (int w = 0; w < wid; ++w) before += wcnt[w];
    int kept = (myu > vstar) ? 1 : (eq ? (before < need) : 0);
    float gate = kept ? tanhf(score) : 0.0f;
#pragma unroll
    for (int c = 0; c < MIDC; ++c) h1own[c] *= gate;    // h1own becomes xp (0 if dropped)
    hb4[tid*5+0] = make_float4(h1own[0],  h1own[1],  h1own[2],  h1own[3]);
    hb4[tid*5+1] = make_float4(h1own[4],  h1own[5],  h1own[6],  h1own[7]);
    hb4[tid*5+2] = make_float4(h1own[8],  h1own[9],  h1own[10], h1own[11]);
    hb4[tid*5+3] = make_float4(h1own[12], h1own[13], h1own[14], h1own[15]);
    ubv[tid] = (unsigned)kept;
  }
  __syncthreads();

  // ---- conv2 degree over valid edges; dinv2 ----
  float di2;
  {
    int cnt2 = 0;
    for (int p = beg; p < end; ++p) cnt2 += (int)ubv[csr[p]];
    di2 = rsqrtf((float)(1 + cnt2));
    dinvb[tid] = di2;           // old dinv has no remaining readers
  }
  __syncthreads();

  // ---- gather conv2 (xp already zero for dropped sources) ----
  {
    float acc2[MIDC];
#pragma unroll
    for (int c = 0; c < MIDC; ++c) acc2[c] = 0.0f;
    for (int p = beg; p < end; ++p) {
      int s = csr[p];
      float ds_ = dinvb[s];
      float4 a0 = hb4[s*5+0], a1 = hb4[s*5+1], a2 = hb4[s*5+2], a3 = hb4[s*5+3];
      acc2[0]  += a0.x*ds_; acc2[1]  += a0.y*ds_; acc2[2]  += a0.z*ds_; acc2[3]  += a0.w*ds_;
      acc2[4]  += a1.x*ds_; acc2[5]  += a1.y*ds_; acc2[6]  += a1.z*ds_; acc2[7]  += a1.w*ds_;
      acc2[8]  += a2.x*ds_; acc2[9]  += a2.y*ds_; acc2[10] += a2.z*ds_; acc2[11] += a2.w*ds_;
      acc2[12] += a3.x*ds_; acc2[13] += a3.y*ds_; acc2[14] += a3.z*ds_; acc2[15] += a3.w*ds_;
    }
#pragma unroll
    for (int c = 0; c < MIDC; ++c)
      h1own[c] = di2*acc2[c] + h1own[c]*di2*di2;        // pre2
  }
  __syncthreads();
  hb4[tid*5+0] = make_float4(h1own[0],  h1own[1],  h1own[2],  h1own[3]);
  hb4[tid*5+1] = make_float4(h1own[4],  h1own[5],  h1own[6],  h1own[7]);
  hb4[tid*5+2] = make_float4(h1own[8],  h1own[9],  h1own[10], h1own[11]);
  hb4[tid*5+3] = make_float4(h1own[12], h1own[13], h1own[14], h1own[15]);
  __syncthreads();

  // ---- out2 = relu(pre2 @ W2 + b2); mean pool over kept nodes ----
  {
    const int ig = tid >> 6, h4 = tid & 63;
    float4 w2c[MIDC];
#pragma unroll
    for (int c = 0; c < MIDC; ++c) w2c[c] = *(const float4*)(W2 + c*HH + (h4 << 2));
    float4 bv = *(const float4*)(b2 + (h4 << 2));
    float4 pacc = make_float4(0.f, 0.f, 0.f, 0.f);
    for (int k = 0; k < 64; ++k) {
      int i = (ig << 6) + k;                 // wave-uniform -> LDS broadcasts
      if (ubv[i] == 0u) continue;
      float4 v0 = hb4[i*5+0], v1 = hb4[i*5+1], v2 = hb4[i*5+2], v3 = hb4[i*5+3];
      float vv[MIDC] = {v0.x,v0.y,v0.z,v0.w, v1.x,v1.y,v1.z,v1.w,
                        v2.x,v2.y,v2.z,v2.w, v3.x,v3.y,v3.z,v3.w};
      float t0 = bv.x, t1 = bv.y, t2 = bv.z, t3 = bv.w;
#pragma unroll
      for (int c = 0; c < MIDC; ++c) {
        t0 += vv[c]*w2c[c].x; t1 += vv[c]*w2c[c].y;
        t2 += vv[c]*w2c[c].z; t3 += vv[c]*w2c[c].w;
      }
      pacc.x += fmaxf(t0, 0.f); pacc.y += fmaxf(t1, 0.f);
      pacc.z += fmaxf(t2, 0.f); pacc.w += fmaxf(t3, 0.f);
    }
    float4* part4 = (float4*)(sm + OFF_CSR);           // reuse CSR space: [16][256]
    part4[(ig << 6) + h4] = pacc;
  }
  __syncthreads();
  if (tid < HH) {
    const float* part = sm + OFF_CSR;
    float s = 0.f;
#pragma unroll
    for (int ig = 0; ig < 16; ++ig) s += part[ig*HH + tid];
    emb[(size_t)g*HH + tid] = s * (1.0f/(float)KK);
  }
}

// ---------------------------------------------------------------------------
// K_LSTM: fused gate-precompute + 16 LSTM steps + classifier in ONE kernel.
// Replaces k_gatepre + 16x k_step + k_cls (was ~250us of launch/latency
// overhead for ~134 MFLOP of actual work).
//
// grid = 256 blocks = (unit-group ug 0..15) x (batch b 0..15), 256 threads.
// bid = ug*16 + b  (blocks of one batch 16 apart -> same XCD under %8
// round-robin; only a perf heuristic, never correctness).
//
// Per block:
//  - 64 W_hh rows (4 gates x 16 units) held in REGISTERS for all 16 steps
//    (4x4 float4 = 64 VGPR): zero per-step weight traffic.
//  - A-slice A_s[t][4*16] = emb[t,b,:]@W_ih_rows + b_ih + b_hh computed once
//    into LDS (k_gatepre folded; A never touches global).
//  - per step: read full h[b] (1KB, device-scope loads) -> LDS, GEMV from
//    registers, 16 shfl-reduced dots per gate, c kept in registers of
//    tid<16, write 16 h values (device-scope), then per-batch 16-block
//    spin barrier on a monotonic device-scope counter (double-buffered h).
//  - t==15: classifier partial shfl-reduced, one atomicAdd per block.
//
// Co-residency (deadlock safety): 256 blocks x (4 waves, ~22KB LDS,
// <=128 VGPR) -> >=4 blocks fit per CU; 256 CUs; all blocks resident even
// under pathological dispatch skew.
// ---------------------------------------------------------------------------
__global__ __launch_bounds__(256) void k_lstm(
    const float* __restrict__ emb, const float* __restrict__ W_ih,
    const float* __restrict__ W_hh, const float* __restrict__ b_ih,
    const float* __restrict__ b_hh, const float* __restrict__ clsW,
    const float* __restrict__ clsb, float* __restrict__ hA,
    float* __restrict__ hB, int* __restrict__ bar, float* __restrict__ out)
{
  __shared__ __align__(16) float emb_s[16][HH];   // 16 KB
  __shared__ __align__(16) float A_s[16][64];     // 4 KB, [t][gate*16+ul]
  __shared__ __align__(16) float h_s[HH];         // 1 KB
  __shared__ float gl[16][4];

  const int bid = blockIdx.x;
  const int b   = bid & 15, ug = bid >> 4;
  const int tid = threadIdx.x;
  const int ul  = tid >> 4, sub = tid & 15;       // 16 lanes per row-dot
  const int u   = ug*16 + ul;                     // global unit of this 16-group

  // ---- stage emb rows for batch b (coalesced) ----
  for (int i = tid; i < 16*HH; i += 256) {
    int t = i >> 8, k = i & 255;
    emb_s[t][k] = emb[(size_t)(t*BB + b)*HH + k];
  }

  // ---- W_hh fragments into registers (held for all 16 steps) ----
  float4 wh[4][4];
#pragma unroll
  for (int g_ = 0; g_ < 4; ++g_) {
    const float4* wr = (const float4*)(W_hh + (size_t)(g_*HH + u)*HH);
    wh[g_][0] = wr[sub];      wh[g_][1] = wr[sub+16];
    wh[g_][2] = wr[sub+32];   wh[g_][3] = wr[sub+48];
  }
  __syncthreads();

  // ---- A_s[t][g*16+ul] = emb[t,b,:] . W_ih[row] + b_ih[row] + b_hh[row] ----
#pragma unroll
  for (int g_ = 0; g_ < 4; ++g_) {
    const int j = g_*HH + u;                       // PyTorch row = gate*256+unit
    const float4* wr = (const float4*)(W_ih + (size_t)j*HH);
    float4 w0 = wr[sub], w1 = wr[sub+16], w2 = wr[sub+32], w3 = wr[sub+48];
    float bj = b_ih[j] + b_hh[j];
    for (int t = 0; t < 16; ++t) {
      const float4* e4 = (const float4*)emb_s[t]; // same addr for all 16-groups -> broadcast
      float4 e0 = e4[sub], e1 = e4[sub+16], e2 = e4[sub+32], e3 = e4[sub+48];
      float p = w0.x*e0.x + w0.y*e0.y + w0.z*e0.z + w0.w*e0.w
              + w1.x*e1.x + w1.y*e1.y + w1.z*e1.z + w1.w*e1.w
              + w2.x*e2.x + w2.y*e2.y + w2.z*e2.z + w2.w*e2.w
              + w3.x*e3.x + w3.y*e3.y + w3.z*e3.z + w3.w*e3.w;
      p += __shfl_xor(p, 1); p += __shfl_xor(p, 2);
      p += __shfl_xor(p, 4); p += __shfl_xor(p, 8);
      if (sub == 0) A_s[t][g_*16 + ul] = p + bj;
    }
  }
  __syncthreads();

  // ---- 16 recurrent steps ----
  float c = 0.0f;                                  // c for unit ug*16+tid (tid<16)
  for (int s = 0; s < 16; ++s) {
    if (s == 0) {
      h_s[tid] = 0.0f;
    } else {
      const float* hr = (s & 1) ? hA : hB;         // read buffer = prev write buffer
      h_s[tid] = __hip_atomic_load(&hr[b*HH + tid], __ATOMIC_RELAXED,
                                   __HIP_MEMORY_SCOPE_AGENT);
    }
    __syncthreads();

    const float4* h4 = (const float4*)h_s;
    float4 hv0 = h4[sub], hv1 = h4[sub+16], hv2 = h4[sub+32], hv3 = h4[sub+48];
    float gv[4];
#pragma unroll
    for (int g_ = 0; g_ < 4; ++g_) {
      float p = wh[g_][0].x*hv0.x + wh[g_][0].y*hv0.y + wh[g_][0].z*hv0.z + wh[g_][0].w*hv0.w
              + wh[g_][1].x*hv1.x + wh[g_][1].y*hv1.y + wh[g_][1].z*hv1.z + wh[g_][1].w*hv1.w
              + wh[g_][2].x*hv2.x + wh[g_][2].y*hv2.y + wh[g_][2].z*hv2.z + wh[g_][2].w*hv2.w
              + wh[g_][3].x*hv3.x + wh[g_][3].y*hv3.y + wh[g_][3].z*hv3.z + wh[g_][3].w*hv3.w;
      p += __shfl_xor(p, 1); p += __shfl_xor(p, 2);
      p += __shfl_xor(p, 4); p += __shfl_xor(p, 8);
      gv[g_] = p;
    }
    if (sub == 0) { gl[ul][0]=gv[0]; gl[ul][1]=gv[1]; gl[ul][2]=gv[2]; gl[ul][3]=gv[3]; }
    __syncthreads();

    if (tid < 16) {
      float gi = gl[tid][0] + A_s[s][     tid];
      float gf = gl[tid][1] + A_s[s][16 + tid];
      float gn = gl[tid][2] + A_s[s][32 + tid];
      float go = gl[tid][3] + A_s[s][48 + tid];
      float iv = 1.0f/(1.0f + expf(-gi));
      float fv = 1.0f/(1.0f + expf(-gf));
      float gg = tanhf(gn);
      float ov = 1.0f/(1.0f + expf(-go));
      c = fv*c + iv*gg;
      float hv = ov * tanhf(c);
      float* hw = (s & 1) ? hB : hA;               // write buffer
      __hip_atomic_store(&hw[b*HH + ug*16 + tid], hv, __ATOMIC_RELAXED,
                         __HIP_MEMORY_SCOPE_AGENT);
      if (s == 15) {                               // fold classifier
        float p = hv * clsW[ug*16 + tid];
        p += __shfl_xor(p, 1); p += __shfl_xor(p, 2);
        p += __shfl_xor(p, 4); p += __shfl_xor(p, 8);
        if (tid == 0) atomicAdd(&out[b], p + (ug == 0 ? clsb[0] : 0.0f));
      }
    }

    if (s < 15) {
      // per-batch 16-block barrier; monotonic counter, zeroed per launch
      __syncthreads();                             // drains vmcnt: h stores complete
      if (tid == 0) {
        __threadfence();                           // release: publish h writes
        atomicAdd(&bar[b], 1);
        const int target = 16 * (s + 1);
        while (__hip_atomic_load(&bar[b], __ATOMIC_RELAXED,
                                 __HIP_MEMORY_SCOPE_AGENT) < target)
          __builtin_amdgcn_s_sleep(4);
        __threadfence();                           // acquire: see remote h writes
      }
      __syncthreads();
    }
  }
}

// ---------------------------------------------------------------------------
extern "C" void kernel_launch(void* const* d_in, const int* in_sizes, int n_in,
                              void* d_out, int out_size, void* d_ws, size_t ws_size,
                              hipStream_t stream)
{
  const float* x    = (const float*)d_in[0];
  const int*   ei   = (const int*)  d_in[1];
  const float* W1   = (const float*)d_in[2];
  const float* b1   = (const float*)d_in[3];
  const float* Wl   = (const float*)d_in[4];
  const float* Wr   = (const float*)d_in[5];
  const float* bs   = (const float*)d_in[6];
  const float* W2   = (const float*)d_in[7];
  const float* b2   = (const float*)d_in[8];
  const float* Wih  = (const float*)d_in[9];
  const float* Whh  = (const float*)d_in[10];
  const float* bih  = (const float*)d_in[11];
  const float* bhh  = (const float*)d_in[12];
  const float* clsW = (const float*)d_in[13];
  const float* clsb = (const float*)d_in[14];
  float* out = (float*)d_out;

  float* emb = (float*)d_ws;                    // [T*B, 256]  (live through k_lstm)
  float* hA  = emb + (size_t)TT*BB*HH;          // [16][256] h double-buffer A
  float* hB  = hA + BB*HH;                      // [16][256] h double-buffer B
  int*   bar = (int*)(hB + BB*HH);              // [16] per-batch barrier counters

  (void)hipFuncSetAttribute(reinterpret_cast<const void*>(k_graph),
      hipFuncAttributeMaxDynamicSharedMemorySize, SM_BYTES);

  hipLaunchKernelGGL(k_graph, dim3(TT*BB), dim3(1024), SM_BYTES, stream,
                     x, ei, W1, b1, Wl, Wr, bs, W2, b2, emb);
  (void)hipMemsetAsync(bar, 0, BB*sizeof(int), stream);
  (void)hipMemsetAsync(out, 0, BB*sizeof(float), stream);
  hipLaunchKernelGGL(k_lstm, dim3(256), dim3(256), 0, stream,
                     emb, Wih, Whh, bih, bhh, clsW, clsb, hA, hB, bar, out);
}

// Round 2
// 434.918 us; speedup vs baseline: 1.4221x; 1.4221x over previous
//
#include <hip/hip_runtime.h>
#include <cmath>

#define TT 16
#define BB 16
#define NN 1024
#define EE 16384
#define FIN 128
#define MIDC 16
#define HH 256
#define KK 820
#define HS 20           // hbuf row stride in floats (80 B, 16 B aligned for ds_read_b128)

// ---- LDS float-slot layout for k_graph ----
#define OFF_HBUF   0
#define N_HBUF     (NN*HS)                    // 20480
#define OFF_CSR    (OFF_HBUF + N_HBUF)        // ushort[EE] -> 8192 float slots (reused as partials[16][256] at the end)
#define N_CSR      (EE/2)
#define OFF_HEAD   (OFF_CSR + N_CSR)          // int[NN+1]
#define OFF_CUR    (OFF_HEAD + NN + 1)        // int[NN]
#define OFF_SCANA  (OFF_CUR + NN)             // int[NN]
#define OFF_DINV   (OFF_SCANA + NN)           // float[NN] (aliases scanB during the prefix scan)
#define OFF_UB     (OFF_DINV + NN)            // uint[NN] kept mask
#define OFF_HIST   (OFF_UB + NN)              // int[256]
#define OFF_S      (OFF_HIST + 256)           // int[256] suffix sums
#define OFF_WCNT   (OFF_S + 256)              // int[16]
#define OFF_CTRL   (OFF_WCNT + 16)            // int[8]
#define SM_FLOATS  (OFF_CTRL + 8)
#define SM_BYTES   (SM_FLOATS * 4)            // ~137.3 KB

// ---------------------------------------------------------------------------
// K1: one block per graph, 1024 threads (= N nodes). conv1 -> CSR build ->
// gather conv1 -> gather SAG -> radix top-K -> gate -> gather conv2 ->
// 16x256 matmul + relu + mean pool.  No float atomics anywhere.
// (UNCHANGED — this round isolates the k_lstm barrier fix)
// ---------------------------------------------------------------------------
__global__ __launch_bounds__(1024) void k_graph(
    const float* __restrict__ x, const int* __restrict__ ei,
    const float* __restrict__ W1, const float* __restrict__ b1,
    const float* __restrict__ Wl, const float* __restrict__ Wr,
    const float* __restrict__ bsag, const float* __restrict__ W2,
    const float* __restrict__ b2, float* __restrict__ emb)
{
  extern __shared__ __align__(16) float sm[];
  float*          hbuf  = sm + OFF_HBUF;
  float4*         hb4   = (float4*)hbuf;
  unsigned short* csr   = (unsigned short*)(sm + OFF_CSR);
  int*            head  = (int*)(sm + OFF_HEAD);
  int*            cur   = (int*)(sm + OFF_CUR);
  int*            scanA = (int*)(sm + OFF_SCANA);
  int*            scanB = (int*)(sm + OFF_DINV);     // alias, freed before dinv use
  float*          dinvb = sm + OFF_DINV;
  unsigned*       ubv   = (unsigned*)(sm + OFF_UB);
  int*            hist  = (int*)(sm + OFF_HIST);
  int*            S     = (int*)(sm + OFF_S);
  int*            wcnt  = (int*)(sm + OFF_WCNT);
  int*            ctrl  = (int*)(sm + OFF_CTRL);

  const int g   = blockIdx.x;
  const int tid = threadIdx.x;
  const float* xg   = x  + (size_t)g * (NN*FIN);
  const int*   srcp = ei + (size_t)g * (2*EE);
  const int*   dstp = srcp + EE;

  cur[tid] = 0;

  // ---- conv1 matmul: hown = x_row @ W1 (W1 via wave-uniform s_loads) ----
  float hown[MIDC];
  {
    const float4* xr = (const float4*)(xg + (size_t)tid * FIN);
#pragma unroll
    for (int c = 0; c < MIDC; ++c) hown[c] = 0.0f;
    for (int k4 = 0; k4 < FIN/4; ++k4) {
      float4 v = xr[k4];
      const float* w0 = W1 + (k4*4 + 0)*MIDC;
      const float* w1 = W1 + (k4*4 + 1)*MIDC;
      const float* w2 = W1 + (k4*4 + 2)*MIDC;
      const float* w3 = W1 + (k4*4 + 3)*MIDC;
#pragma unroll
      for (int c = 0; c < MIDC; ++c)
        hown[c] += v.x*w0[c] + v.y*w1[c] + v.z*w2[c] + v.w*w3[c];
    }
    hb4[tid*5+0] = make_float4(hown[0],  hown[1],  hown[2],  hown[3]);
    hb4[tid*5+1] = make_float4(hown[4],  hown[5],  hown[6],  hown[7]);
    hb4[tid*5+2] = make_float4(hown[8],  hown[9],  hown[10], hown[11]);
    hb4[tid*5+3] = make_float4(hown[12], hown[13], hown[14], hown[15]);
  }
  __syncthreads();

  // ---- degree count (int atomics, native) ----
  for (int e = tid; e < EE; e += 1024) atomicAdd(&cur[dstp[e]], 1);
  __syncthreads();

  // ---- exclusive prefix scan (Hillis-Steele, ping-pong) ----
  {
    int v = cur[tid];
    scanA[tid] = v;
    __syncthreads();
    int* s_ = scanA; int* d_ = scanB;
    for (int off = 1; off < NN; off <<= 1) {
      int t = s_[tid];
      if (tid >= off) t += s_[tid - off];
      d_[tid] = t;
      __syncthreads();
      int* tmp = s_; s_ = d_; d_ = tmp;
    }
    int inc = s_[tid];
    int ex  = inc - v;
    __syncthreads();                 // all scan reads done before dinvb overwrite
    head[tid] = ex;
    cur[tid]  = ex;
    if (tid == 0) head[NN] = EE;
    dinvb[tid] = rsqrtf((float)(v + 1));
  }
  __syncthreads();

  // ---- CSR fill (src ids as ushort) ----
  for (int e = tid; e < EE; e += 1024) {
    int s = srcp[e], d = dstp[e];
    int pos = atomicAdd(&cur[d], 1);
    csr[pos] = (unsigned short)s;
  }
  __syncthreads();

  const int beg = head[tid], end = head[tid+1];

  // ---- gather conv1: acc = sum_s dinv_s * h_s ----
  float h1own[MIDC];
  {
    float accv[MIDC];
#pragma unroll
    for (int c = 0; c < MIDC; ++c) accv[c] = 0.0f;
    for (int p = beg; p < end; ++p) {
      int s = csr[p];
      float ds_ = dinvb[s];
      float4 a0 = hb4[s*5+0], a1 = hb4[s*5+1], a2 = hb4[s*5+2], a3 = hb4[s*5+3];
      accv[0]  += a0.x*ds_; accv[1]  += a0.y*ds_; accv[2]  += a0.z*ds_; accv[3]  += a0.w*ds_;
      accv[4]  += a1.x*ds_; accv[5]  += a1.y*ds_; accv[6]  += a1.z*ds_; accv[7]  += a1.w*ds_;
      accv[8]  += a2.x*ds_; accv[9]  += a2.y*ds_; accv[10] += a2.z*ds_; accv[11] += a2.w*ds_;
      accv[12] += a3.x*ds_; accv[13] += a3.y*ds_; accv[14] += a3.z*ds_; accv[15] += a3.w*ds_;
    }
    float di = dinvb[tid];
#pragma unroll
    for (int c = 0; c < MIDC; ++c)
      h1own[c] = fmaxf(di*accv[c] + hown[c]*di*di + b1[c], 0.0f);
  }
  __syncthreads();
  hb4[tid*5+0] = make_float4(h1own[0],  h1own[1],  h1own[2],  h1own[3]);
  hb4[tid*5+1] = make_float4(h1own[4],  h1own[5],  h1own[6],  h1own[7]);
  hb4[tid*5+2] = make_float4(h1own[8],  h1own[9],  h1own[10], h1own[11]);
  hb4[tid*5+3] = make_float4(h1own[12], h1own[13], h1own[14], h1own[15]);
  __syncthreads();

  // ---- gather SAG: agg = sum_s h1_s ; score ----
  float score;
  unsigned myu;
  {
    float aggv[MIDC];
#pragma unroll
    for (int c = 0; c < MIDC; ++c) aggv[c] = 0.0f;
    for (int p = beg; p < end; ++p) {
      int s = csr[p];
      float4 a0 = hb4[s*5+0], a1 = hb4[s*5+1], a2 = hb4[s*5+2], a3 = hb4[s*5+3];
      aggv[0]  += a0.x; aggv[1]  += a0.y; aggv[2]  += a0.z; aggv[3]  += a0.w;
      aggv[4]  += a1.x; aggv[5]  += a1.y; aggv[6]  += a1.z; aggv[7]  += a1.w;
      aggv[8]  += a2.x; aggv[9]  += a2.y; aggv[10] += a2.z; aggv[11] += a2.w;
      aggv[12] += a3.x; aggv[13] += a3.y; aggv[14] += a3.z; aggv[15] += a3.w;
    }
    score = bsag[0];
#pragma unroll
    for (int c = 0; c < MIDC; ++c) score += aggv[c]*Wl[c] + h1own[c]*Wr[c];
    unsigned ubits = __float_as_uint(score);
    myu = (ubits & 0x80000000u) ? ~ubits : (ubits | 0x80000000u);
  }

  // ---- radix select K-th largest key (parallel suffix scan per round) ----
  int remK = KK;
  unsigned pref = 0;
  for (int byte = 3; byte >= 0; --byte) {
    if (tid < 256) hist[tid] = 0;
    __syncthreads();
    const int sh = byte * 8;
    const unsigned hi_mask = (byte == 3) ? 0u : (0xFFFFFFFFu << (sh + 8));
    if ((myu & hi_mask) == pref) atomicAdd(&hist[(myu >> sh) & 255u], 1);
    __syncthreads();
    if (tid < 64) {
      int h0 = hist[tid*4+0], h1_ = hist[tid*4+1], h2_ = hist[tid*4+2], h3_ = hist[tid*4+3];
      int s3 = h3_, s2 = h2_ + s3, s1 = h1_ + s2, s0 = h0 + s1;
      int run = s0;
#pragma unroll
      for (int off = 1; off < 64; off <<= 1) {
        int o = __shfl_down(run, off);
        if (tid + off < 64) run += o;
      }
      int above = run - s0;
      S[tid*4+0] = above + s0;
      S[tid*4+1] = above + s1;
      S[tid*4+2] = above + s2;
      S[tid*4+3] = above + s3;
    }
    __syncthreads();
    if (tid < 256) {
      int Sv = S[tid];
      int Sn = (tid < 255) ? S[tid+1] : 0;
      if (Sv >= remK && Sn < remK) { ctrl[0] = remK - Sn; ctrl[1] = tid; }
    }
    __syncthreads();
    remK  = ctrl[0];
    pref |= ((unsigned)ctrl[1]) << sh;
    __syncthreads();
  }
  const unsigned vstar = pref;
  const int need = remK;

  // ---- kept mask: ties broken by lowest index (ballot-based count) ----
  {
    const int wid = tid >> 6, lane = tid & 63;
    bool eq = (myu == vstar);
    unsigned long long m = __ballot(eq);
    if (lane == 0) wcnt[wid] = __popcll(m);
    __syncthreads();
    int before = (lane == 0) ? 0 : __popcll(m & ((~0ull) >> (64 - lane)));
    for (int w = 0; w < wid; ++w) before += wcnt[w];
    int kept = (myu > vstar) ? 1 : (eq ? (before < need) : 0);
    float gate = kept ? tanhf(score) : 0.0f;
#pragma unroll
    for (int c = 0; c < MIDC; ++c) h1own[c] *= gate;    // h1own becomes xp (0 if dropped)
    hb4[tid*5+0] = make_float4(h1own[0],  h1own[1],  h1own[2],  h1own[3]);
    hb4[tid*5+1] = make_float4(h1own[4],  h1own[5],  h1own[6],  h1own[7]);
    hb4[tid*5+2] = make_float4(h1own[8],  h1own[9],  h1own[10], h1own[11]);
    hb4[tid*5+3] = make_float4(h1own[12], h1own[13], h1own[14], h1own[15]);
    ubv[tid] = (unsigned)kept;
  }
  __syncthreads();

  // ---- conv2 degree over valid edges; dinv2 ----
  float di2;
  {
    int cnt2 = 0;
    for (int p = beg; p < end; ++p) cnt2 += (int)ubv[csr[p]];
    di2 = rsqrtf((float)(1 + cnt2));
    dinvb[tid] = di2;           // old dinv has no remaining readers
  }
  __syncthreads();

  // ---- gather conv2 (xp already zero for dropped sources) ----
  {
    float acc2[MIDC];
#pragma unroll
    for (int c = 0; c < MIDC; ++c) acc2[c] = 0.0f;
    for (int p = beg; p < end; ++p) {
      int s = csr[p];
      float ds_ = dinvb[s];
      float4 a0 = hb4[s*5+0], a1 = hb4[s*5+1], a2 = hb4[s*5+2], a3 = hb4[s*5+3];
      acc2[0]  += a0.x*ds_; acc2[1]  += a0.y*ds_; acc2[2]  += a0.z*ds_; acc2[3]  += a0.w*ds_;
      acc2[4]  += a1.x*ds_; acc2[5]  += a1.y*ds_; acc2[6]  += a1.z*ds_; acc2[7]  += a1.w*ds_;
      acc2[8]  += a2.x*ds_; acc2[9]  += a2.y*ds_; acc2[10] += a2.z*ds_; acc2[11] += a2.w*ds_;
      acc2[12] += a3.x*ds_; acc2[13] += a3.y*ds_; acc2[14] += a3.z*ds_; acc2[15] += a3.w*ds_;
    }
#pragma unroll
    for (int c = 0; c < MIDC; ++c)
      h1own[c] = di2*acc2[c] + h1own[c]*di2*di2;        // pre2
  }
  __syncthreads();
  hb4[tid*5+0] = make_float4(h1own[0],  h1own[1],  h1own[2],  h1own[3]);
  hb4[tid*5+1] = make_float4(h1own[4],  h1own[5],  h1own[6],  h1own[7]);
  hb4[tid*5+2] = make_float4(h1own[8],  h1own[9],  h1own[10], h1own[11]);
  hb4[tid*5+3] = make_float4(h1own[12], h1own[13], h1own[14], h1own[15]);
  __syncthreads();

  // ---- out2 = relu(pre2 @ W2 + b2); mean pool over kept nodes ----
  {
    const int ig = tid >> 6, h4 = tid & 63;
    float4 w2c[MIDC];
#pragma unroll
    for (int c = 0; c < MIDC; ++c) w2c[c] = *(const float4*)(W2 + c*HH + (h4 << 2));
    float4 bv = *(const float4*)(b2 + (h4 << 2));
    float4 pacc = make_float4(0.f, 0.f, 0.f, 0.f);
    for (int k = 0; k < 64; ++k) {
      int i = (ig << 6) + k;                 // wave-uniform -> LDS broadcasts
      if (ubv[i] == 0u) continue;
      float4 v0 = hb4[i*5+0], v1 = hb4[i*5+1], v2 = hb4[i*5+2], v3 = hb4[i*5+3];
      float vv[MIDC] = {v0.x,v0.y,v0.z,v0.w, v1.x,v1.y,v1.z,v1.w,
                        v2.x,v2.y,v2.z,v2.w, v3.x,v3.y,v3.z,v3.w};
      float t0 = bv.x, t1 = bv.y, t2 = bv.z, t3 = bv.w;
#pragma unroll
      for (int c = 0; c < MIDC; ++c) {
        t0 += vv[c]*w2c[c].x; t1 += vv[c]*w2c[c].y;
        t2 += vv[c]*w2c[c].z; t3 += vv[c]*w2c[c].w;
      }
      pacc.x += fmaxf(t0, 0.f); pacc.y += fmaxf(t1, 0.f);
      pacc.z += fmaxf(t2, 0.f); pacc.w += fmaxf(t3, 0.f);
    }
    float4* part4 = (float4*)(sm + OFF_CSR);           // reuse CSR space: [16][256]
    part4[(ig << 6) + h4] = pacc;
  }
  __syncthreads();
  if (tid < HH) {
    const float* part = sm + OFF_CSR;
    float s = 0.f;
#pragma unroll
    for (int ig = 0; ig < 16; ++ig) s += part[ig*HH + tid];
    emb[(size_t)g*HH + tid] = s * (1.0f/(float)KK);
  }
}

// ---------------------------------------------------------------------------
// K_LSTM: fused gate-precompute + 16 LSTM steps + classifier in ONE kernel.
//
// ROUND-2 CHANGE (isolated): the inter-block barrier no longer uses
// __threadfence().  __threadfence() = seq-cst agent fence = buffer_wbl2 +
// buffer_inv (full L2 writeback/invalidate walk).  256 blocks x 2 fences x
// 15 steps serialized those walks at each XCD's L2 -> ~19us/step (measured
// 284us, VALUBusy 1.6%).  The fences are unnecessary:
//  - h loads/stores are AGENT-scope relaxed atomics (sc0 sc1 flagged) ->
//    they bypass the non-coherent L1/L2 and hit the coherent point; no
//    invalidate needed for them to see remote data.
//  - release ordering (h visible before counter bump): h stores (tid<16)
//    and the bar add (tid 0) are in the SAME wave; __syncthreads() emits
//    s_waitcnt vmcnt(0) before s_barrier, draining the sc1 stores to the
//    coherent point before tid 0 can increment.
//  - acquire ordering: readers' h loads are themselves sc-flagged and sit
//    after the spin + __syncthreads(); nothing stale to invalidate.
//
// grid = 256 blocks = (unit-group ug) x (batch b); bid = ug*16+b so all 16
// blocks of a batch land on XCD b%8 under %8 round-robin (perf heuristic).
// W_hh rows live in registers for all 16 steps; A (gate-precompute) in LDS;
// classifier folded at t=15.  Co-residency: 1 block/CU over 256 CUs.
// ---------------------------------------------------------------------------
__global__ __launch_bounds__(256) void k_lstm(
    const float* __restrict__ emb, const float* __restrict__ W_ih,
    const float* __restrict__ W_hh, const float* __restrict__ b_ih,
    const float* __restrict__ b_hh, const float* __restrict__ clsW,
    const float* __restrict__ clsb, float* __restrict__ hA,
    float* __restrict__ hB, int* __restrict__ bar, float* __restrict__ out)
{
  __shared__ __align__(16) float emb_s[16][HH];   // 16 KB
  __shared__ __align__(16) float A_s[16][64];     // 4 KB, [t][gate*16+ul]
  __shared__ __align__(16) float h_s[HH];         // 1 KB
  __shared__ float gl[16][4];

  const int bid = blockIdx.x;
  const int b   = bid & 15, ug = bid >> 4;
  const int tid = threadIdx.x;
  const int ul  = tid >> 4, sub = tid & 15;       // 16 lanes per row-dot
  const int u   = ug*16 + ul;                     // global unit of this 16-group

  // ---- stage emb rows for batch b (coalesced) ----
  for (int i = tid; i < 16*HH; i += 256) {
    int t = i >> 8, k = i & 255;
    emb_s[t][k] = emb[(size_t)(t*BB + b)*HH + k];
  }

  // ---- W_hh fragments into registers (held for all 16 steps) ----
  float4 wh[4][4];
#pragma unroll
  for (int g_ = 0; g_ < 4; ++g_) {
    const float4* wr = (const float4*)(W_hh + (size_t)(g_*HH + u)*HH);
    wh[g_][0] = wr[sub];      wh[g_][1] = wr[sub+16];
    wh[g_][2] = wr[sub+32];   wh[g_][3] = wr[sub+48];
  }
  __syncthreads();

  // ---- A_s[t][g*16+ul] = emb[t,b,:] . W_ih[row] + b_ih[row] + b_hh[row] ----
#pragma unroll
  for (int g_ = 0; g_ < 4; ++g_) {
    const int j = g_*HH + u;                       // PyTorch row = gate*256+unit
    const float4* wr = (const float4*)(W_ih + (size_t)j*HH);
    float4 w0 = wr[sub], w1 = wr[sub+16], w2 = wr[sub+32], w3 = wr[sub+48];
    float bj = b_ih[j] + b_hh[j];
    for (int t = 0; t < 16; ++t) {
      const float4* e4 = (const float4*)emb_s[t]; // same addr for all 16-groups -> broadcast
      float4 e0 = e4[sub], e1 = e4[sub+16], e2 = e4[sub+32], e3 = e4[sub+48];
      float p = w0.x*e0.x + w0.y*e0.y + w0.z*e0.z + w0.w*e0.w
              + w1.x*e1.x + w1.y*e1.y + w1.z*e1.z + w1.w*e1.w
              + w2.x*e2.x + w2.y*e2.y + w2.z*e2.z + w2.w*e2.w
              + w3.x*e3.x + w3.y*e3.y + w3.z*e3.z + w3.w*e3.w;
      p += __shfl_xor(p, 1); p += __shfl_xor(p, 2);
      p += __shfl_xor(p, 4); p += __shfl_xor(p, 8);
      if (sub == 0) A_s[t][g_*16 + ul] = p + bj;
    }
  }
  __syncthreads();

  // ---- 16 recurrent steps ----
  float c = 0.0f;                                  // c for unit ug*16+tid (tid<16)
  for (int s = 0; s < 16; ++s) {
    if (s == 0) {
      h_s[tid] = 0.0f;
    } else {
      const float* hr = (s & 1) ? hA : hB;         // read buffer = prev write buffer
      h_s[tid] = __hip_atomic_load(&hr[b*HH + tid], __ATOMIC_RELAXED,
                                   __HIP_MEMORY_SCOPE_AGENT);
    }
    __syncthreads();

    const float4* h4 = (const float4*)h_s;
    float4 hv0 = h4[sub], hv1 = h4[sub+16], hv2 = h4[sub+32], hv3 = h4[sub+48];
    float gv[4];
#pragma unroll
    for (int g_ = 0; g_ < 4; ++g_) {
      float p = wh[g_][0].x*hv0.x + wh[g_][0].y*hv0.y + wh[g_][0].z*hv0.z + wh[g_][0].w*hv0.w
              + wh[g_][1].x*hv1.x + wh[g_][1].y*hv1.y + wh[g_][1].z*hv1.z + wh[g_][1].w*hv1.w
              + wh[g_][2].x*hv2.x + wh[g_][2].y*hv2.y + wh[g_][2].z*hv2.z + wh[g_][2].w*hv2.w
              + wh[g_][3].x*hv3.x + wh[g_][3].y*hv3.y + wh[g_][3].z*hv3.z + wh[g_][3].w*hv3.w;
      p += __shfl_xor(p, 1); p += __shfl_xor(p, 2);
      p += __shfl_xor(p, 4); p += __shfl_xor(p, 8);
      gv[g_] = p;
    }
    if (sub == 0) { gl[ul][0]=gv[0]; gl[ul][1]=gv[1]; gl[ul][2]=gv[2]; gl[ul][3]=gv[3]; }
    __syncthreads();

    if (tid < 16) {
      float gi = gl[tid][0] + A_s[s][     tid];
      float gf = gl[tid][1] + A_s[s][16 + tid];
      float gn = gl[tid][2] + A_s[s][32 + tid];
      float go = gl[tid][3] + A_s[s][48 + tid];
      float iv = 1.0f/(1.0f + expf(-gi));
      float fv = 1.0f/(1.0f + expf(-gf));
      float gg = tanhf(gn);
      float ov = 1.0f/(1.0f + expf(-go));
      c = fv*c + iv*gg;
      float hv = ov * tanhf(c);
      float* hw = (s & 1) ? hB : hA;               // write buffer
      __hip_atomic_store(&hw[b*HH + ug*16 + tid], hv, __ATOMIC_RELAXED,
                         __HIP_MEMORY_SCOPE_AGENT);
      if (s == 15) {                               // fold classifier
        float p = hv * clsW[ug*16 + tid];
        p += __shfl_xor(p, 1); p += __shfl_xor(p, 2);
        p += __shfl_xor(p, 4); p += __shfl_xor(p, 8);
        if (tid == 0) atomicAdd(&out[b], p + (ug == 0 ? clsb[0] : 0.0f));
      }
    }

    if (s < 15) {
      // per-batch 16-block barrier; monotonic counter, zeroed per launch.
      // __syncthreads drains vmcnt(0): the sc1 h-stores (same wave as tid 0)
      // are at the coherent point before the counter increments -> release
      // ordering without any L2 writeback/invalidate.
      __syncthreads();
      if (tid == 0) {
        __hip_atomic_fetch_add(&bar[b], 1, __ATOMIC_RELAXED,
                               __HIP_MEMORY_SCOPE_AGENT);
        const int target = 16 * (s + 1);
        while (__hip_atomic_load(&bar[b], __ATOMIC_RELAXED,
                                 __HIP_MEMORY_SCOPE_AGENT) < target)
          __builtin_amdgcn_s_sleep(1);
      }
      __syncthreads();
    }
  }
}

// ---------------------------------------------------------------------------
extern "C" void kernel_launch(void* const* d_in, const int* in_sizes, int n_in,
                              void* d_out, int out_size, void* d_ws, size_t ws_size,
                              hipStream_t stream)
{
  const float* x    = (const float*)d_in[0];
  const int*   ei   = (const int*)  d_in[1];
  const float* W1   = (const float*)d_in[2];
  const float* b1   = (const float*)d_in[3];
  const float* Wl   = (const float*)d_in[4];
  const float* Wr   = (const float*)d_in[5];
  const float* bs   = (const float*)d_in[6];
  const float* W2   = (const float*)d_in[7];
  const float* b2   = (const float*)d_in[8];
  const float* Wih  = (const float*)d_in[9];
  const float* Whh  = (const float*)d_in[10];
  const float* bih  = (const float*)d_in[11];
  const float* bhh  = (const float*)d_in[12];
  const float* clsW = (const float*)d_in[13];
  const float* clsb = (const float*)d_in[14];
  float* out = (float*)d_out;

  float* emb = (float*)d_ws;                    // [T*B, 256]  (live through k_lstm)
  float* hA  = emb + (size_t)TT*BB*HH;          // [16][256] h double-buffer A
  float* hB  = hA + BB*HH;                      // [16][256] h double-buffer B
  int*   bar = (int*)(hB + BB*HH);              // [16] per-batch barrier counters

  (void)hipFuncSetAttribute(reinterpret_cast<const void*>(k_graph),
      hipFuncAttributeMaxDynamicSharedMemorySize, SM_BYTES);

  hipLaunchKernelGGL(k_graph, dim3(TT*BB), dim3(1024), SM_BYTES, stream,
                     x, ei, W1, b1, Wl, Wr, bs, W2, b2, emb);
  (void)hipMemsetAsync(bar, 0, BB*sizeof(int), stream);
  (void)hipMemsetAsync(out, 0, BB*sizeof(float), stream);
  hipLaunchKernelGGL(k_lstm, dim3(256), dim3(256), 0, stream,
                     emb, Wih, Whh, bih, bhh, clsW, clsb, hA, hB, bar, out);
}

// Round 3
// 391.004 us; speedup vs baseline: 1.5818x; 1.1123x over previous
//
#include <hip/hip_runtime.h>
#include <cmath>

#define TT 16
#define BB 16
#define NN 1024
#define EE 16384
#define FIN 128
#define MIDC 16
#define HH 256
#define KK 820
#define HS 20           // hbuf row stride in floats (80 B, 16 B aligned for ds_read_b128)

// ---- LDS float-slot layout for k_graph ----
#define OFF_HBUF   0
#define N_HBUF     (NN*HS)                    // 20480
#define OFF_CSR    (OFF_HBUF + N_HBUF)        // ushort[EE] -> 8192 float slots (reused as partials[16][256] at the end)
#define N_CSR      (EE/2)
#define OFF_HEAD   (OFF_CSR + N_CSR)          // int[NN+1]
#define OFF_CUR    (OFF_HEAD + NN + 1)        // int[NN]
#define OFF_SCANA  (OFF_CUR + NN)             // int[NN] (unused since r3 wave-scan; kept for layout stability)
#define OFF_DINV   (OFF_SCANA + NN)           // float[NN]
#define OFF_UB     (OFF_DINV + NN)            // uint[NN] kept mask
#define OFF_HIST   (OFF_UB + NN)              // int[256]
#define OFF_S      (OFF_HIST + 256)           // int[256] suffix sums
#define OFF_WCNT   (OFF_S + 256)              // int[16]
#define OFF_CTRL   (OFF_WCNT + 16)            // int[8]
#define SM_FLOATS  (OFF_CTRL + 8)
#define SM_BYTES   (SM_FLOATS * 4)            // ~137.3 KB

// ---------------------------------------------------------------------------
// K1: one block per graph, 1024 threads (= N nodes). conv1 -> CSR build ->
// gather conv1 -> gather SAG -> radix top-K -> gate -> gather conv2 ->
// 16x256 matmul + relu + mean pool.  No float atomics anywhere.
// ROUND-3 CHANGE (bit-exact): Hillis-Steele scan (10 barriers, 20 LDS
// sweeps) -> two-level __shfl_up wave scan (2 barriers). Integer math,
// identical results.
// ---------------------------------------------------------------------------
__global__ __launch_bounds__(1024) void k_graph(
    const float* __restrict__ x, const int* __restrict__ ei,
    const float* __restrict__ W1, const float* __restrict__ b1,
    const float* __restrict__ Wl, const float* __restrict__ Wr,
    const float* __restrict__ bsag, const float* __restrict__ W2,
    const float* __restrict__ b2, float* __restrict__ emb)
{
  extern __shared__ __align__(16) float sm[];
  float*          hbuf  = sm + OFF_HBUF;
  float4*         hb4   = (float4*)hbuf;
  unsigned short* csr   = (unsigned short*)(sm + OFF_CSR);
  int*            head  = (int*)(sm + OFF_HEAD);
  int*            cur   = (int*)(sm + OFF_CUR);
  float*          dinvb = sm + OFF_DINV;
  unsigned*       ubv   = (unsigned*)(sm + OFF_UB);
  int*            hist  = (int*)(sm + OFF_HIST);
  int*            S     = (int*)(sm + OFF_S);
  int*            wcnt  = (int*)(sm + OFF_WCNT);
  int*            ctrl  = (int*)(sm + OFF_CTRL);

  const int g   = blockIdx.x;
  const int tid = threadIdx.x;
  const float* xg   = x  + (size_t)g * (NN*FIN);
  const int*   srcp = ei + (size_t)g * (2*EE);
  const int*   dstp = srcp + EE;

  cur[tid] = 0;

  // ---- conv1 matmul: hown = x_row @ W1 (W1 via wave-uniform s_loads) ----
  float hown[MIDC];
  {
    const float4* xr = (const float4*)(xg + (size_t)tid * FIN);
#pragma unroll
    for (int c = 0; c < MIDC; ++c) hown[c] = 0.0f;
    for (int k4 = 0; k4 < FIN/4; ++k4) {
      float4 v = xr[k4];
      const float* w0 = W1 + (k4*4 + 0)*MIDC;
      const float* w1 = W1 + (k4*4 + 1)*MIDC;
      const float* w2 = W1 + (k4*4 + 2)*MIDC;
      const float* w3 = W1 + (k4*4 + 3)*MIDC;
#pragma unroll
      for (int c = 0; c < MIDC; ++c)
        hown[c] += v.x*w0[c] + v.y*w1[c] + v.z*w2[c] + v.w*w3[c];
    }
    hb4[tid*5+0] = make_float4(hown[0],  hown[1],  hown[2],  hown[3]);
    hb4[tid*5+1] = make_float4(hown[4],  hown[5],  hown[6],  hown[7]);
    hb4[tid*5+2] = make_float4(hown[8],  hown[9],  hown[10], hown[11]);
    hb4[tid*5+3] = make_float4(hown[12], hown[13], hown[14], hown[15]);
  }
  __syncthreads();

  // ---- degree count (int atomics, native) ----
  for (int e = tid; e < EE; e += 1024) atomicAdd(&cur[dstp[e]], 1);
  __syncthreads();

  // ---- exclusive prefix scan: two-level shfl wave scan (exact, 2 barriers) ----
  {
    const int lane_ = tid & 63, wid_ = tid >> 6;
    int v = cur[tid];
    int xscan = v;                    // becomes intra-wave inclusive scan
#pragma unroll
    for (int off = 1; off < 64; off <<= 1) {
      int y = __shfl_up(xscan, off);
      if (lane_ >= off) xscan += y;
    }
    if (lane_ == 63) wcnt[wid_] = xscan;       // wave totals
    __syncthreads();
    if (tid < 64) {
      int w = (tid < 16) ? wcnt[tid] : 0;
#pragma unroll
      for (int off = 1; off < 16; off <<= 1) {
        int y = __shfl_up(w, off);
        if (tid >= off) w += y;
      }
      if (tid < 16) wcnt[tid] = w;             // inclusive scan of wave totals
    }
    __syncthreads();
    int ex = xscan - v + ((wid_ == 0) ? 0 : wcnt[wid_ - 1]);
    head[tid] = ex;
    cur[tid]  = ex;
    if (tid == 0) head[NN] = EE;
    dinvb[tid] = rsqrtf((float)(v + 1));
  }
  __syncthreads();

  // ---- CSR fill (src ids as ushort) ----
  for (int e = tid; e < EE; e += 1024) {
    int s = srcp[e], d = dstp[e];
    int pos = atomicAdd(&cur[d], 1);
    csr[pos] = (unsigned short)s;
  }
  __syncthreads();

  const int beg = head[tid], end = head[tid+1];

  // ---- gather conv1: acc = sum_s dinv_s * h_s ----
  float h1own[MIDC];
  {
    float accv[MIDC];
#pragma unroll
    for (int c = 0; c < MIDC; ++c) accv[c] = 0.0f;
    for (int p = beg; p < end; ++p) {
      int s = csr[p];
      float ds_ = dinvb[s];
      float4 a0 = hb4[s*5+0], a1 = hb4[s*5+1], a2 = hb4[s*5+2], a3 = hb4[s*5+3];
      accv[0]  += a0.x*ds_; accv[1]  += a0.y*ds_; accv[2]  += a0.z*ds_; accv[3]  += a0.w*ds_;
      accv[4]  += a1.x*ds_; accv[5]  += a1.y*ds_; accv[6]  += a1.z*ds_; accv[7]  += a1.w*ds_;
      accv[8]  += a2.x*ds_; accv[9]  += a2.y*ds_; accv[10] += a2.z*ds_; accv[11] += a2.w*ds_;
      accv[12] += a3.x*ds_; accv[13] += a3.y*ds_; accv[14] += a3.z*ds_; accv[15] += a3.w*ds_;
    }
    float di = dinvb[tid];
#pragma unroll
    for (int c = 0; c < MIDC; ++c)
      h1own[c] = fmaxf(di*accv[c] + hown[c]*di*di + b1[c], 0.0f);
  }
  __syncthreads();
  hb4[tid*5+0] = make_float4(h1own[0],  h1own[1],  h1own[2],  h1own[3]);
  hb4[tid*5+1] = make_float4(h1own[4],  h1own[5],  h1own[6],  h1own[7]);
  hb4[tid*5+2] = make_float4(h1own[8],  h1own[9],  h1own[10], h1own[11]);
  hb4[tid*5+3] = make_float4(h1own[12], h1own[13], h1own[14], h1own[15]);
  __syncthreads();

  // ---- gather SAG: agg = sum_s h1_s ; score ----
  float score;
  unsigned myu;
  {
    float aggv[MIDC];
#pragma unroll
    for (int c = 0; c < MIDC; ++c) aggv[c] = 0.0f;
    for (int p = beg; p < end; ++p) {
      int s = csr[p];
      float4 a0 = hb4[s*5+0], a1 = hb4[s*5+1], a2 = hb4[s*5+2], a3 = hb4[s*5+3];
      aggv[0]  += a0.x; aggv[1]  += a0.y; aggv[2]  += a0.z; aggv[3]  += a0.w;
      aggv[4]  += a1.x; aggv[5]  += a1.y; aggv[6]  += a1.z; aggv[7]  += a1.w;
      aggv[8]  += a2.x; aggv[9]  += a2.y; aggv[10] += a2.z; aggv[11] += a2.w;
      aggv[12] += a3.x; aggv[13] += a3.y; aggv[14] += a3.z; aggv[15] += a3.w;
    }
    score = bsag[0];
#pragma unroll
    for (int c = 0; c < MIDC; ++c) score += aggv[c]*Wl[c] + h1own[c]*Wr[c];
    unsigned ubits = __float_as_uint(score);
    myu = (ubits & 0x80000000u) ? ~ubits : (ubits | 0x80000000u);
  }

  // ---- radix select K-th largest key (parallel suffix scan per round) ----
  int remK = KK;
  unsigned pref = 0;
  for (int byte = 3; byte >= 0; --byte) {
    if (tid < 256) hist[tid] = 0;
    __syncthreads();
    const int sh = byte * 8;
    const unsigned hi_mask = (byte == 3) ? 0u : (0xFFFFFFFFu << (sh + 8));
    if ((myu & hi_mask) == pref) atomicAdd(&hist[(myu >> sh) & 255u], 1);
    __syncthreads();
    if (tid < 64) {
      int h0 = hist[tid*4+0], h1_ = hist[tid*4+1], h2_ = hist[tid*4+2], h3_ = hist[tid*4+3];
      int s3 = h3_, s2 = h2_ + s3, s1 = h1_ + s2, s0 = h0 + s1;
      int run = s0;
#pragma unroll
      for (int off = 1; off < 64; off <<= 1) {
        int o = __shfl_down(run, off);
        if (tid + off < 64) run += o;
      }
      int above = run - s0;
      S[tid*4+0] = above + s0;
      S[tid*4+1] = above + s1;
      S[tid*4+2] = above + s2;
      S[tid*4+3] = above + s3;
    }
    __syncthreads();
    if (tid < 256) {
      int Sv = S[tid];
      int Sn = (tid < 255) ? S[tid+1] : 0;
      if (Sv >= remK && Sn < remK) { ctrl[0] = remK - Sn; ctrl[1] = tid; }
    }
    __syncthreads();
    remK  = ctrl[0];
    pref |= ((unsigned)ctrl[1]) << sh;
    __syncthreads();
  }
  const unsigned vstar = pref;
  const int need = remK;

  // ---- kept mask: ties broken by lowest index (ballot-based count) ----
  {
    const int wid = tid >> 6, lane = tid & 63;
    bool eq = (myu == vstar);
    unsigned long long m = __ballot(eq);
    if (lane == 0) wcnt[wid] = __popcll(m);
    __syncthreads();
    int before = (lane == 0) ? 0 : __popcll(m & ((~0ull) >> (64 - lane)));
    for (int w = 0; w < wid; ++w) before += wcnt[w];
    int kept = (myu > vstar) ? 1 : (eq ? (before < need) : 0);
    float gate = kept ? tanhf(score) : 0.0f;
#pragma unroll
    for (int c = 0; c < MIDC; ++c) h1own[c] *= gate;    // h1own becomes xp (0 if dropped)
    hb4[tid*5+0] = make_float4(h1own[0],  h1own[1],  h1own[2],  h1own[3]);
    hb4[tid*5+1] = make_float4(h1own[4],  h1own[5],  h1own[6],  h1own[7]);
    hb4[tid*5+2] = make_float4(h1own[8],  h1own[9],  h1own[10], h1own[11]);
    hb4[tid*5+3] = make_float4(h1own[12], h1own[13], h1own[14], h1own[15]);
    ubv[tid] = (unsigned)kept;
  }
  __syncthreads();

  // ---- conv2 degree over valid edges; dinv2 ----
  float di2;
  {
    int cnt2 = 0;
    for (int p = beg; p < end; ++p) cnt2 += (int)ubv[csr[p]];
    di2 = rsqrtf((float)(1 + cnt2));
    dinvb[tid] = di2;           // old dinv has no remaining readers
  }
  __syncthreads();

  // ---- gather conv2 (xp already zero for dropped sources) ----
  {
    float acc2[MIDC];
#pragma unroll
    for (int c = 0; c < MIDC; ++c) acc2[c] = 0.0f;
    for (int p = beg; p < end; ++p) {
      int s = csr[p];
      float ds_ = dinvb[s];
      float4 a0 = hb4[s*5+0], a1 = hb4[s*5+1], a2 = hb4[s*5+2], a3 = hb4[s*5+3];
      acc2[0]  += a0.x*ds_; acc2[1]  += a0.y*ds_; acc2[2]  += a0.z*ds_; acc2[3]  += a0.w*ds_;
      acc2[4]  += a1.x*ds_; acc2[5]  += a1.y*ds_; acc2[6]  += a1.z*ds_; acc2[7]  += a1.w*ds_;
      acc2[8]  += a2.x*ds_; acc2[9]  += a2.y*ds_; acc2[10] += a2.z*ds_; acc2[11] += a2.w*ds_;
      acc2[12] += a3.x*ds_; acc2[13] += a3.y*ds_; acc2[14] += a3.z*ds_; acc2[15] += a3.w*ds_;
    }
#pragma unroll
    for (int c = 0; c < MIDC; ++c)
      h1own[c] = di2*acc2[c] + h1own[c]*di2*di2;        // pre2
  }
  __syncthreads();
  hb4[tid*5+0] = make_float4(h1own[0],  h1own[1],  h1own[2],  h1own[3]);
  hb4[tid*5+1] = make_float4(h1own[4],  h1own[5],  h1own[6],  h1own[7]);
  hb4[tid*5+2] = make_float4(h1own[8],  h1own[9],  h1own[10], h1own[11]);
  hb4[tid*5+3] = make_float4(h1own[12], h1own[13], h1own[14], h1own[15]);
  __syncthreads();

  // ---- out2 = relu(pre2 @ W2 + b2); mean pool over kept nodes ----
  {
    const int ig = tid >> 6, h4 = tid & 63;
    float4 w2c[MIDC];
#pragma unroll
    for (int c = 0; c < MIDC; ++c) w2c[c] = *(const float4*)(W2 + c*HH + (h4 << 2));
    float4 bv = *(const float4*)(b2 + (h4 << 2));
    float4 pacc = make_float4(0.f, 0.f, 0.f, 0.f);
    for (int k = 0; k < 64; ++k) {
      int i = (ig << 6) + k;                 // wave-uniform -> LDS broadcasts
      if (ubv[i] == 0u) continue;
      float4 v0 = hb4[i*5+0], v1 = hb4[i*5+1], v2 = hb4[i*5+2], v3 = hb4[i*5+3];
      float vv[MIDC] = {v0.x,v0.y,v0.z,v0.w, v1.x,v1.y,v1.z,v1.w,
                        v2.x,v2.y,v2.z,v2.w, v3.x,v3.y,v3.z,v3.w};
      float t0 = bv.x, t1 = bv.y, t2 = bv.z, t3 = bv.w;
#pragma unroll
      for (int c = 0; c < MIDC; ++c) {
        t0 += vv[c]*w2c[c].x; t1 += vv[c]*w2c[c].y;
        t2 += vv[c]*w2c[c].z; t3 += vv[c]*w2c[c].w;
      }
      pacc.x += fmaxf(t0, 0.f); pacc.y += fmaxf(t1, 0.f);
      pacc.z += fmaxf(t2, 0.f); pacc.w += fmaxf(t3, 0.f);
    }
    float4* part4 = (float4*)(sm + OFF_CSR);           // reuse CSR space: [16][256]
    part4[(ig << 6) + h4] = pacc;
  }
  __syncthreads();
  if (tid < HH) {
    const float* part = sm + OFF_CSR;
    float s = 0.f;
#pragma unroll
    for (int ig = 0; ig < 16; ++ig) s += part[ig*HH + tid];
    emb[(size_t)g*HH + tid] = s * (1.0f/(float)KK);
  }
}

// ---------------------------------------------------------------------------
// K_LSTM: fused gate-precompute + 16 LSTM steps + classifier in ONE kernel.
//
// ROUND-3 CHANGE (isolated): counter barrier (16 serialized agent-scope
// atomicAdds on ONE address per step -> ~3-5us/step of RMW contention at
// the coherent point) replaced by a contention-free FLAG barrier:
//  - each block STOREs its own step-stamp flags[b*16+ug] = s+1 (plain
//    relaxed agent store, no RMW, 16 parallel stores to 16 addresses);
//  - wave 0 polls all 16 flags in parallel (lane i watches flag i) and
//    exits on __all(fv >= s+1).
// Ordering is the validated r2 pattern: __syncthreads() drains vmcnt
// (h-stores at the coherent point) before the flag store; readers' h loads
// are sc-flagged (cache-bypassing) and sit behind the poll + barrier.
// Flags are monotonic within a launch (1..15) and memset to 0 per launch.
// ---------------------------------------------------------------------------
__global__ __launch_bounds__(256) void k_lstm(
    const float* __restrict__ emb, const float* __restrict__ W_ih,
    const float* __restrict__ W_hh, const float* __restrict__ b_ih,
    const float* __restrict__ b_hh, const float* __restrict__ clsW,
    const float* __restrict__ clsb, float* __restrict__ hA,
    float* __restrict__ hB, int* __restrict__ flags, float* __restrict__ out)
{
  __shared__ __align__(16) float emb_s[16][HH];   // 16 KB
  __shared__ __align__(16) float A_s[16][64];     // 4 KB, [t][gate*16+ul]
  __shared__ __align__(16) float h_s[HH];         // 1 KB
  __shared__ float gl[16][4];

  const int bid = blockIdx.x;
  const int b   = bid & 15, ug = bid >> 4;
  const int tid = threadIdx.x;
  const int ul  = tid >> 4, sub = tid & 15;       // 16 lanes per row-dot
  const int u   = ug*16 + ul;                     // global unit of this 16-group

  // ---- stage emb rows for batch b (coalesced) ----
  for (int i = tid; i < 16*HH; i += 256) {
    int t = i >> 8, k = i & 255;
    emb_s[t][k] = emb[(size_t)(t*BB + b)*HH + k];
  }

  // ---- W_hh fragments into registers (held for all 16 steps) ----
  float4 wh[4][4];
#pragma unroll
  for (int g_ = 0; g_ < 4; ++g_) {
    const float4* wr = (const float4*)(W_hh + (size_t)(g_*HH + u)*HH);
    wh[g_][0] = wr[sub];      wh[g_][1] = wr[sub+16];
    wh[g_][2] = wr[sub+32];   wh[g_][3] = wr[sub+48];
  }
  __syncthreads();

  // ---- A_s[t][g*16+ul] = emb[t,b,:] . W_ih[row] + b_ih[row] + b_hh[row] ----
#pragma unroll
  for (int g_ = 0; g_ < 4; ++g_) {
    const int j = g_*HH + u;                       // PyTorch row = gate*256+unit
    const float4* wr = (const float4*)(W_ih + (size_t)j*HH);
    float4 w0 = wr[sub], w1 = wr[sub+16], w2 = wr[sub+32], w3 = wr[sub+48];
    float bj = b_ih[j] + b_hh[j];
    for (int t = 0; t < 16; ++t) {
      const float4* e4 = (const float4*)emb_s[t]; // same addr for all 16-groups -> broadcast
      float4 e0 = e4[sub], e1 = e4[sub+16], e2 = e4[sub+32], e3 = e4[sub+48];
      float p = w0.x*e0.x + w0.y*e0.y + w0.z*e0.z + w0.w*e0.w
              + w1.x*e1.x + w1.y*e1.y + w1.z*e1.z + w1.w*e1.w
              + w2.x*e2.x + w2.y*e2.y + w2.z*e2.z + w2.w*e2.w
              + w3.x*e3.x + w3.y*e3.y + w3.z*e3.z + w3.w*e3.w;
      p += __shfl_xor(p, 1); p += __shfl_xor(p, 2);
      p += __shfl_xor(p, 4); p += __shfl_xor(p, 8);
      if (sub == 0) A_s[t][g_*16 + ul] = p + bj;
    }
  }
  __syncthreads();

  // ---- 16 recurrent steps ----
  float c = 0.0f;                                  // c for unit ug*16+tid (tid<16)
  for (int s = 0; s < 16; ++s) {
    if (s == 0) {
      h_s[tid] = 0.0f;
    } else {
      const float* hr = (s & 1) ? hA : hB;         // read buffer = prev write buffer
      h_s[tid] = __hip_atomic_load(&hr[b*HH + tid], __ATOMIC_RELAXED,
                                   __HIP_MEMORY_SCOPE_AGENT);
    }
    __syncthreads();

    const float4* h4 = (const float4*)h_s;
    float4 hv0 = h4[sub], hv1 = h4[sub+16], hv2 = h4[sub+32], hv3 = h4[sub+48];
    float gv[4];
#pragma unroll
    for (int g_ = 0; g_ < 4; ++g_) {
      float p = wh[g_][0].x*hv0.x + wh[g_][0].y*hv0.y + wh[g_][0].z*hv0.z + wh[g_][0].w*hv0.w
              + wh[g_][1].x*hv1.x + wh[g_][1].y*hv1.y + wh[g_][1].z*hv1.z + wh[g_][1].w*hv1.w
              + wh[g_][2].x*hv2.x + wh[g_][2].y*hv2.y + wh[g_][2].z*hv2.z + wh[g_][2].w*hv2.w
              + wh[g_][3].x*hv3.x + wh[g_][3].y*hv3.y + wh[g_][3].z*hv3.z + wh[g_][3].w*hv3.w;
      p += __shfl_xor(p, 1); p += __shfl_xor(p, 2);
      p += __shfl_xor(p, 4); p += __shfl_xor(p, 8);
      gv[g_] = p;
    }
    if (sub == 0) { gl[ul][0]=gv[0]; gl[ul][1]=gv[1]; gl[ul][2]=gv[2]; gl[ul][3]=gv[3]; }
    __syncthreads();

    if (tid < 16) {
      float gi = gl[tid][0] + A_s[s][     tid];
      float gf = gl[tid][1] + A_s[s][16 + tid];
      float gn = gl[tid][2] + A_s[s][32 + tid];
      float go = gl[tid][3] + A_s[s][48 + tid];
      float iv = 1.0f/(1.0f + expf(-gi));
      float fv = 1.0f/(1.0f + expf(-gf));
      float gg = tanhf(gn);
      float ov = 1.0f/(1.0f + expf(-go));
      c = fv*c + iv*gg;
      float hv = ov * tanhf(c);
      float* hw = (s & 1) ? hB : hA;               // write buffer
      __hip_atomic_store(&hw[b*HH + ug*16 + tid], hv, __ATOMIC_RELAXED,
                         __HIP_MEMORY_SCOPE_AGENT);
      if (s == 15) {                               // fold classifier
        float p = hv * clsW[ug*16 + tid];
        p += __shfl_xor(p, 1); p += __shfl_xor(p, 2);
        p += __shfl_xor(p, 4); p += __shfl_xor(p, 8);
        if (tid == 0) atomicAdd(&out[b], p + (ug == 0 ? clsb[0] : 0.0f));
      }
    }

    if (s < 15) {
      // flag barrier: store own stamp (no RMW), poll all 16 in parallel.
      __syncthreads();                             // drains vmcnt: h stores visible
      if (tid == 0)
        __hip_atomic_store(&flags[(b << 4) + ug], s + 1, __ATOMIC_RELAXED,
                           __HIP_MEMORY_SCOPE_AGENT);
      if (tid < 64) {                              // wave 0: lane i watches flag i
        const int target = s + 1;
        for (;;) {
          int fv = __hip_atomic_load(&flags[(b << 4) + (tid & 15)],
                                     __ATOMIC_RELAXED, __HIP_MEMORY_SCOPE_AGENT);
          if (__all(fv >= target)) break;
          __builtin_amdgcn_s_sleep(1);
        }
      }
      __syncthreads();
    }
  }
}

// ---------------------------------------------------------------------------
extern "C" void kernel_launch(void* const* d_in, const int* in_sizes, int n_in,
                              void* d_out, int out_size, void* d_ws, size_t ws_size,
                              hipStream_t stream)
{
  const float* x    = (const float*)d_in[0];
  const int*   ei   = (const int*)  d_in[1];
  const float* W1   = (const float*)d_in[2];
  const float* b1   = (const float*)d_in[3];
  const float* Wl   = (const float*)d_in[4];
  const float* Wr   = (const float*)d_in[5];
  const float* bs   = (const float*)d_in[6];
  const float* W2   = (const float*)d_in[7];
  const float* b2   = (const float*)d_in[8];
  const float* Wih  = (const float*)d_in[9];
  const float* Whh  = (const float*)d_in[10];
  const float* bih  = (const float*)d_in[11];
  const float* bhh  = (const float*)d_in[12];
  const float* clsW = (const float*)d_in[13];
  const float* clsb = (const float*)d_in[14];
  float* out = (float*)d_out;

  float* emb   = (float*)d_ws;                  // [T*B, 256]  (live through k_lstm)
  float* hA    = emb + (size_t)TT*BB*HH;        // [16][256] h double-buffer A
  float* hB    = hA + BB*HH;                    // [16][256] h double-buffer B
  int*   flags = (int*)(hB + BB*HH);            // [16][16] per-(batch,block) step stamps

  (void)hipFuncSetAttribute(reinterpret_cast<const void*>(k_graph),
      hipFuncAttributeMaxDynamicSharedMemorySize, SM_BYTES);

  hipLaunchKernelGGL(k_graph, dim3(TT*BB), dim3(1024), SM_BYTES, stream,
                     x, ei, W1, b1, Wl, Wr, bs, W2, b2, emb);
  (void)hipMemsetAsync(flags, 0, BB*BB*sizeof(int), stream);
  (void)hipMemsetAsync(out, 0, BB*sizeof(float), stream);
  hipLaunchKernelGGL(k_lstm, dim3(256), dim3(256), 0, stream,
                     emb, Wih, Whh, bih, bhh, clsW, clsb, hA, hB, flags, out);
}

// Round 5
// 386.817 us; speedup vs baseline: 1.5989x; 1.0108x over previous
//
#include <hip/hip_runtime.h>
#include <cmath>

#define TT 16
#define BB 16
#define NN 1024
#define EE 16384
#define FIN 128
#define MIDC 16
#define HH 256
#define KK 820
#define HS 20           // hbuf row stride in floats (80 B, 16 B aligned for ds_read_b128)

// ---- LDS float-slot layout for k_graph ----
#define OFF_HBUF   0
#define N_HBUF     (NN*HS)                    // 20480
#define OFF_CSR    (OFF_HBUF + N_HBUF)        // ushort[EE] -> 8192 float slots (reused as partials[16][256] at the end)
#define N_CSR      (EE/2)
#define OFF_HEAD   (OFF_CSR + N_CSR)          // int[NN+1]
#define OFF_CUR    (OFF_HEAD + NN + 1)        // int[NN]
#define OFF_SCANA  (OFF_CUR + NN)             // float[NN]: q = h1.Wl for scalar SAG gather (r4)
#define OFF_DINV   (OFF_SCANA + NN)           // float[NN]
#define OFF_UB     (OFF_DINV + NN)            // uint[NN] kept mask
#define OFF_HIST   (OFF_UB + NN)              // int[256]
#define OFF_S      (OFF_HIST + 256)           // int[256] suffix sums
#define OFF_WCNT   (OFF_S + 256)              // int[16]
#define OFF_CTRL   (OFF_WCNT + 16)            // int[8]
#define SM_FLOATS  (OFF_CTRL + 8)
#define SM_BYTES   (SM_FLOATS * 4)            // ~137.3 KB

// ---------------------------------------------------------------------------
// K1: one block per graph, 1024 threads (= N nodes).
// (r4 changes retained, untested due to container failure:
//  (a) scalar SAG gather (1 ds_read_b32/edge instead of 4x b128 + 16 FMA);
//  (b) 2-deep software pipeline in conv1/conv2 gathers.)
// ---------------------------------------------------------------------------
__global__ __launch_bounds__(1024) void k_graph(
    const float* __restrict__ x, const int* __restrict__ ei,
    const float* __restrict__ W1, const float* __restrict__ b1,
    const float* __restrict__ Wl, const float* __restrict__ Wr,
    const float* __restrict__ bsag, const float* __restrict__ W2,
    const float* __restrict__ b2, float* __restrict__ emb)
{
  extern __shared__ __align__(16) float sm[];
  float*          hbuf  = sm + OFF_HBUF;
  float4*         hb4   = (float4*)hbuf;
  unsigned short* csr   = (unsigned short*)(sm + OFF_CSR);
  int*            head  = (int*)(sm + OFF_HEAD);
  int*            cur   = (int*)(sm + OFF_CUR);
  float*          qbuf  = sm + OFF_SCANA;
  float*          dinvb = sm + OFF_DINV;
  unsigned*       ubv   = (unsigned*)(sm + OFF_UB);
  int*            hist  = (int*)(sm + OFF_HIST);
  int*            S     = (int*)(sm + OFF_S);
  int*            wcnt  = (int*)(sm + OFF_WCNT);
  int*            ctrl  = (int*)(sm + OFF_CTRL);

  const int g   = blockIdx.x;
  const int tid = threadIdx.x;
  const float* xg   = x  + (size_t)g * (NN*FIN);
  const int*   srcp = ei + (size_t)g * (2*EE);
  const int*   dstp = srcp + EE;

  cur[tid] = 0;

  // ---- conv1 matmul: hown = x_row @ W1 (W1 via wave-uniform s_loads) ----
  float hown[MIDC];
  {
    const float4* xr = (const float4*)(xg + (size_t)tid * FIN);
#pragma unroll
    for (int c = 0; c < MIDC; ++c) hown[c] = 0.0f;
    for (int k4 = 0; k4 < FIN/4; ++k4) {
      float4 v = xr[k4];
      const float* w0 = W1 + (k4*4 + 0)*MIDC;
      const float* w1 = W1 + (k4*4 + 1)*MIDC;
      const float* w2 = W1 + (k4*4 + 2)*MIDC;
      const float* w3 = W1 + (k4*4 + 3)*MIDC;
#pragma unroll
      for (int c = 0; c < MIDC; ++c)
        hown[c] += v.x*w0[c] + v.y*w1[c] + v.z*w2[c] + v.w*w3[c];
    }
    hb4[tid*5+0] = make_float4(hown[0],  hown[1],  hown[2],  hown[3]);
    hb4[tid*5+1] = make_float4(hown[4],  hown[5],  hown[6],  hown[7]);
    hb4[tid*5+2] = make_float4(hown[8],  hown[9],  hown[10], hown[11]);
    hb4[tid*5+3] = make_float4(hown[12], hown[13], hown[14], hown[15]);
  }
  __syncthreads();

  // ---- degree count (int atomics, native) ----
  for (int e = tid; e < EE; e += 1024) atomicAdd(&cur[dstp[e]], 1);
  __syncthreads();

  // ---- exclusive prefix scan: two-level shfl wave scan (exact, 2 barriers) ----
  {
    const int lane_ = tid & 63, wid_ = tid >> 6;
    int v = cur[tid];
    int xscan = v;                    // becomes intra-wave inclusive scan
#pragma unroll
    for (int off = 1; off < 64; off <<= 1) {
      int y = __shfl_up(xscan, off);
      if (lane_ >= off) xscan += y;
    }
    if (lane_ == 63) wcnt[wid_] = xscan;       // wave totals
    __syncthreads();
    if (tid < 64) {
      int w = (tid < 16) ? wcnt[tid] : 0;
#pragma unroll
      for (int off = 1; off < 16; off <<= 1) {
        int y = __shfl_up(w, off);
        if (tid >= off) w += y;
      }
      if (tid < 16) wcnt[tid] = w;             // inclusive scan of wave totals
    }
    __syncthreads();
    int ex = xscan - v + ((wid_ == 0) ? 0 : wcnt[wid_ - 1]);
    head[tid] = ex;
    cur[tid]  = ex;
    if (tid == 0) head[NN] = EE;
    dinvb[tid] = rsqrtf((float)(v + 1));
  }
  __syncthreads();

  // ---- CSR fill (src ids as ushort) ----
  for (int e = tid; e < EE; e += 1024) {
    int s = srcp[e], d = dstp[e];
    int pos = atomicAdd(&cur[d], 1);
    csr[pos] = (unsigned short)s;
  }
  __syncthreads();

  const int beg = head[tid], end = head[tid+1];

  // ---- gather conv1: acc = sum_s dinv_s * h_s  (2-deep pipelined) ----
  float h1own[MIDC];
  {
    float accv[MIDC];
#pragma unroll
    for (int c = 0; c < MIDC; ++c) accv[c] = 0.0f;
    if (beg < end) {
      int sC = csr[beg];
      float4 a0 = hb4[sC*5+0], a1 = hb4[sC*5+1], a2 = hb4[sC*5+2], a3 = hb4[sC*5+3];
      float dsC = dinvb[sC];
      for (int p = beg; p < end; ++p) {
        float4 b0 = a0, b1 = a1, b2 = a2, b3 = a3;
        float dsB = dsC;
        if (p + 1 < end) {                     // prefetch next edge's row
          int sN = csr[p+1];
          a0 = hb4[sN*5+0]; a1 = hb4[sN*5+1]; a2 = hb4[sN*5+2]; a3 = hb4[sN*5+3];
          dsC = dinvb[sN];
        }
        accv[0]  += b0.x*dsB; accv[1]  += b0.y*dsB; accv[2]  += b0.z*dsB; accv[3]  += b0.w*dsB;
        accv[4]  += b1.x*dsB; accv[5]  += b1.y*dsB; accv[6]  += b1.z*dsB; accv[7]  += b1.w*dsB;
        accv[8]  += b2.x*dsB; accv[9]  += b2.y*dsB; accv[10] += b2.z*dsB; accv[11] += b2.w*dsB;
        accv[12] += b3.x*dsB; accv[13] += b3.y*dsB; accv[14] += b3.z*dsB; accv[15] += b3.w*dsB;
      }
    }
    float di = dinvb[tid];
#pragma unroll
    for (int c = 0; c < MIDC; ++c)
      h1own[c] = fmaxf(di*accv[c] + hown[c]*di*di + b1[c], 0.0f);
  }
  __syncthreads();
  hb4[tid*5+0] = make_float4(h1own[0],  h1own[1],  h1own[2],  h1own[3]);
  hb4[tid*5+1] = make_float4(h1own[4],  h1own[5],  h1own[6],  h1own[7]);
  hb4[tid*5+2] = make_float4(h1own[8],  h1own[9],  h1own[10], h1own[11]);
  hb4[tid*5+3] = make_float4(h1own[12], h1own[13], h1own[14], h1own[15]);
  // q = h1 . Wl once per node -> SAG gather becomes scalar sums
  {
    float q = 0.0f;
#pragma unroll
    for (int c = 0; c < MIDC; ++c) q += h1own[c]*Wl[c];
    qbuf[tid] = q;
  }
  __syncthreads();

  // ---- gather SAG (scalar): score = sum_s q_s + h1.Wr + b ----
  float score;
  unsigned myu;
  {
    float qsum = 0.0f;
    for (int p = beg; p < end; ++p) qsum += qbuf[csr[p]];
    score = bsag[0] + qsum;
#pragma unroll
    for (int c = 0; c < MIDC; ++c) score += h1own[c]*Wr[c];
    unsigned ubits = __float_as_uint(score);
    myu = (ubits & 0x80000000u) ? ~ubits : (ubits | 0x80000000u);
  }

  // ---- radix select K-th largest key (parallel suffix scan per round) ----
  int remK = KK;
  unsigned pref = 0;
  for (int byte = 3; byte >= 0; --byte) {
    if (tid < 256) hist[tid] = 0;
    __syncthreads();
    const int sh = byte * 8;
    const unsigned hi_mask = (byte == 3) ? 0u : (0xFFFFFFFFu << (sh + 8));
    if ((myu & hi_mask) == pref) atomicAdd(&hist[(myu >> sh) & 255u], 1);
    __syncthreads();
    if (tid < 64) {
      int h0 = hist[tid*4+0], h1_ = hist[tid*4+1], h2_ = hist[tid*4+2], h3_ = hist[tid*4+3];
      int s3 = h3_, s2 = h2_ + s3, s1 = h1_ + s2, s0 = h0 + s1;
      int run = s0;
#pragma unroll
      for (int off = 1; off < 64; off <<= 1) {
        int o = __shfl_down(run, off);
        if (tid + off < 64) run += o;
      }
      int above = run - s0;
      S[tid*4+0] = above + s0;
      S[tid*4+1] = above + s1;
      S[tid*4+2] = above + s2;
      S[tid*4+3] = above + s3;
    }
    __syncthreads();
    if (tid < 256) {
      int Sv = S[tid];
      int Sn = (tid < 255) ? S[tid+1] : 0;
      if (Sv >= remK && Sn < remK) { ctrl[0] = remK - Sn; ctrl[1] = tid; }
    }
    __syncthreads();
    remK  = ctrl[0];
    pref |= ((unsigned)ctrl[1]) << sh;
    __syncthreads();
  }
  const unsigned vstar = pref;
  const int need = remK;

  // ---- kept mask: ties broken by lowest index (ballot-based count) ----
  {
    const int wid = tid >> 6, lane = tid & 63;
    bool eq = (myu == vstar);
    unsigned long long m = __ballot(eq);
    if (lane == 0) wcnt[wid] = __popcll(m);
    __syncthreads();
    int before = (lane == 0) ? 0 : __popcll(m & ((~0ull) >> (64 - lane)));
    for (int w = 0; w < wid; ++w) before += wcnt[w];
    int kept = (myu > vstar) ? 1 : (eq ? (before < need) : 0);
    float gate = kept ? tanhf(score) : 0.0f;
#pragma unroll
    for (int c = 0; c < MIDC; ++c) h1own[c] *= gate;    // h1own becomes xp (0 if dropped)
    hb4[tid*5+0] = make_float4(h1own[0],  h1own[1],  h1own[2],  h1own[3]);
    hb4[tid*5+1] = make_float4(h1own[4],  h1own[5],  h1own[6],  h1own[7]);
    hb4[tid*5+2] = make_float4(h1own[8],  h1own[9],  h1own[10], h1own[11]);
    hb4[tid*5+3] = make_float4(h1own[12], h1own[13], h1own[14], h1own[15]);
    ubv[tid] = (unsigned)kept;
  }
  __syncthreads();

  // ---- conv2 degree over valid edges; dinv2 ----
  float di2;
  {
    int cnt2 = 0;
    for (int p = beg; p < end; ++p) cnt2 += (int)ubv[csr[p]];
    di2 = rsqrtf((float)(1 + cnt2));
    dinvb[tid] = di2;           // old dinv has no remaining readers
  }
  __syncthreads();

  // ---- gather conv2 (xp already zero for dropped sources; 2-deep pipelined) ----
  {
    float acc2[MIDC];
#pragma unroll
    for (int c = 0; c < MIDC; ++c) acc2[c] = 0.0f;
    if (beg < end) {
      int sC = csr[beg];
      float4 a0 = hb4[sC*5+0], a1 = hb4[sC*5+1], a2 = hb4[sC*5+2], a3 = hb4[sC*5+3];
      float dsC = dinvb[sC];
      for (int p = beg; p < end; ++p) {
        float4 b0 = a0, b1 = a1, b2 = a2, b3 = a3;
        float dsB = dsC;
        if (p + 1 < end) {
          int sN = csr[p+1];
          a0 = hb4[sN*5+0]; a1 = hb4[sN*5+1]; a2 = hb4[sN*5+2]; a3 = hb4[sN*5+3];
          dsC = dinvb[sN];
        }
        acc2[0]  += b0.x*dsB; acc2[1]  += b0.y*dsB; acc2[2]  += b0.z*dsB; acc2[3]  += b0.w*dsB;
        acc2[4]  += b1.x*dsB; acc2[5]  += b1.y*dsB; acc2[6]  += b1.z*dsB; acc2[7]  += b1.w*dsB;
        acc2[8]  += b2.x*dsB; acc2[9]  += b2.y*dsB; acc2[10] += b2.z*dsB; acc2[11] += b2.w*dsB;
        acc2[12] += b3.x*dsB; acc2[13] += b3.y*dsB; acc2[14] += b3.z*dsB; acc2[15] += b3.w*dsB;
      }
    }
#pragma unroll
    for (int c = 0; c < MIDC; ++c)
      h1own[c] = di2*acc2[c] + h1own[c]*di2*di2;        // pre2
  }
  __syncthreads();
  hb4[tid*5+0] = make_float4(h1own[0],  h1own[1],  h1own[2],  h1own[3]);
  hb4[tid*5+1] = make_float4(h1own[4],  h1own[5],  h1own[6],  h1own[7]);
  hb4[tid*5+2] = make_float4(h1own[8],  h1own[9],  h1own[10], h1own[11]);
  hb4[tid*5+3] = make_float4(h1own[12], h1own[13], h1own[14], h1own[15]);
  __syncthreads();

  // ---- out2 = relu(pre2 @ W2 + b2); mean pool over kept nodes ----
  {
    const int ig = tid >> 6, h4 = tid & 63;
    float4 w2c[MIDC];
#pragma unroll
    for (int c = 0; c < MIDC; ++c) w2c[c] = *(const float4*)(W2 + c*HH + (h4 << 2));
    float4 bv = *(const float4*)(b2 + (h4 << 2));
    float4 pacc = make_float4(0.f, 0.f, 0.f, 0.f);
    for (int k = 0; k < 64; ++k) {
      int i = (ig << 6) + k;                 // wave-uniform -> LDS broadcasts
      if (ubv[i] == 0u) continue;
      float4 v0 = hb4[i*5+0], v1 = hb4[i*5+1], v2 = hb4[i*5+2], v3 = hb4[i*5+3];
      float vv[MIDC] = {v0.x,v0.y,v0.z,v0.w, v1.x,v1.y,v1.z,v1.w,
                        v2.x,v2.y,v2.z,v2.w, v3.x,v3.y,v3.z,v3.w};
      float t0 = bv.x, t1 = bv.y, t2 = bv.z, t3 = bv.w;
#pragma unroll
      for (int c = 0; c < MIDC; ++c) {
        t0 += vv[c]*w2c[c].x; t1 += vv[c]*w2c[c].y;
        t2 += vv[c]*w2c[c].z; t3 += vv[c]*w2c[c].w;
      }
      pacc.x += fmaxf(t0, 0.f); pacc.y += fmaxf(t1, 0.f);
      pacc.z += fmaxf(t2, 0.f); pacc.w += fmaxf(t3, 0.f);
    }
    float4* part4 = (float4*)(sm + OFF_CSR);           // reuse CSR space: [16][256]
    part4[(ig << 6) + h4] = pacc;
  }
  __syncthreads();
  if (tid < HH) {
    const float* part = sm + OFF_CSR;
    float s = 0.f;
#pragma unroll
    for (int ig = 0; ig < 16; ++ig) s += part[ig*HH + tid];
    emb[(size_t)g*HH + tid] = s * (1.0f/(float)KK);
  }
}

// ---------------------------------------------------------------------------
// K_LSTM: fused gate-precompute + 16 LSTM steps + classifier in ONE kernel.
//
// ROUND-5 CHANGE (isolated, hang fix): the r4 canary poll spun 65K threads
// on agent-scope LLC loads with NO throttle — suspected livelock (reader
// load storm starving the 16 writer stores at the coherent point) -> the
// container watchdog kill.  Now: one fast check, then s_sleep(1) between
// retries (r3's validated throttle pattern).  ~20x less poll traffic;
// detection latency ~100-200 cycles, well under the step's LLC round trip.
//
// Canary design (r4, logic re-audited clean): per-step fresh buffer
// hstep[s][b][256] pre-memset to 0xFF (-NaN bit pattern, unreachable for
// finite h = sigmoid*tanh).  Writers store h bits relaxed-agent; readers
// poll their own word, drop into LDS, __syncthreads.  One LLC round trip
// per step; no flags; no ABA (buffers never reused within a launch).
// ---------------------------------------------------------------------------
__global__ __launch_bounds__(256) void k_lstm(
    const float* __restrict__ emb, const float* __restrict__ W_ih,
    const float* __restrict__ W_hh, const float* __restrict__ b_ih,
    const float* __restrict__ b_hh, const float* __restrict__ clsW,
    const float* __restrict__ clsb, int* __restrict__ hstep,
    float* __restrict__ out)
{
  __shared__ __align__(16) float emb_s[16][HH];   // 16 KB
  __shared__ __align__(16) float A_s[16][64];     // 4 KB, [t][gate*16+ul]
  __shared__ __align__(16) float h_s[HH];         // 1 KB
  __shared__ float gl[16][4];

  const int bid = blockIdx.x;
  const int b   = bid & 15, ug = bid >> 4;
  const int tid = threadIdx.x;
  const int ul  = tid >> 4, sub = tid & 15;       // 16 lanes per row-dot
  const int u   = ug*16 + ul;                     // global unit of this 16-group

  // ---- stage emb rows for batch b (coalesced) ----
  for (int i = tid; i < 16*HH; i += 256) {
    int t = i >> 8, k = i & 255;
    emb_s[t][k] = emb[(size_t)(t*BB + b)*HH + k];
  }

  // ---- W_hh fragments into registers (held for all 16 steps) ----
  float4 wh[4][4];
#pragma unroll
  for (int g_ = 0; g_ < 4; ++g_) {
    const float4* wr = (const float4*)(W_hh + (size_t)(g_*HH + u)*HH);
    wh[g_][0] = wr[sub];      wh[g_][1] = wr[sub+16];
    wh[g_][2] = wr[sub+32];   wh[g_][3] = wr[sub+48];
  }
  __syncthreads();

  // ---- A_s[t][g*16+ul] = emb[t,b,:] . W_ih[row] + b_ih[row] + b_hh[row] ----
#pragma unroll
  for (int g_ = 0; g_ < 4; ++g_) {
    const int j = g_*HH + u;                       // PyTorch row = gate*256+unit
    const float4* wr = (const float4*)(W_ih + (size_t)j*HH);
    float4 w0 = wr[sub], w1 = wr[sub+16], w2 = wr[sub+32], w3 = wr[sub+48];
    float bj = b_ih[j] + b_hh[j];
    for (int t = 0; t < 16; ++t) {
      const float4* e4 = (const float4*)emb_s[t]; // same addr for all 16-groups -> broadcast
      float4 e0 = e4[sub], e1 = e4[sub+16], e2 = e4[sub+32], e3 = e4[sub+48];
      float p = w0.x*e0.x + w0.y*e0.y + w0.z*e0.z + w0.w*e0.w
              + w1.x*e1.x + w1.y*e1.y + w1.z*e1.z + w1.w*e1.w
              + w2.x*e2.x + w2.y*e2.y + w2.z*e2.z + w2.w*e2.w
              + w3.x*e3.x + w3.y*e3.y + w3.z*e3.z + w3.w*e3.w;
      p += __shfl_xor(p, 1); p += __shfl_xor(p, 2);
      p += __shfl_xor(p, 4); p += __shfl_xor(p, 8);
      if (sub == 0) A_s[t][g_*16 + ul] = p + bj;
    }
  }
  __syncthreads();

  // ---- 16 recurrent steps ----
  float c = 0.0f;                                  // c for unit ug*16+tid (tid<16)
  for (int s = 0; s < 16; ++s) {
    if (s == 0) {
      h_s[tid] = 0.0f;
    } else {
      const int* src = hstep + ((size_t)(s-1)*BB + b)*HH;
      int v = __hip_atomic_load(&src[tid], __ATOMIC_RELAXED,
                                __HIP_MEMORY_SCOPE_AGENT);
      while (v == -1) {                            // canary: -NaN, unreachable
        __builtin_amdgcn_s_sleep(1);               // throttle: no LLC load storm
        v = __hip_atomic_load(&src[tid], __ATOMIC_RELAXED,
                              __HIP_MEMORY_SCOPE_AGENT);
      }
      h_s[tid] = __int_as_float(v);
    }
    __syncthreads();

    const float4* h4 = (const float4*)h_s;
    float4 hv0 = h4[sub], hv1 = h4[sub+16], hv2 = h4[sub+32], hv3 = h4[sub+48];
    float gv[4];
#pragma unroll
    for (int g_ = 0; g_ < 4; ++g_) {
      float p = wh[g_][0].x*hv0.x + wh[g_][0].y*hv0.y + wh[g_][0].z*hv0.z + wh[g_][0].w*hv0.w
              + wh[g_][1].x*hv1.x + wh[g_][1].y*hv1.y + wh[g_][1].z*hv1.z + wh[g_][1].w*hv1.w
              + wh[g_][2].x*hv2.x + wh[g_][2].y*hv2.y + wh[g_][2].z*hv2.z + wh[g_][2].w*hv2.w
              + wh[g_][3].x*hv3.x + wh[g_][3].y*hv3.y + wh[g_][3].z*hv3.z + wh[g_][3].w*hv3.w;
      p += __shfl_xor(p, 1); p += __shfl_xor(p, 2);
      p += __shfl_xor(p, 4); p += __shfl_xor(p, 8);
      gv[g_] = p;
    }
    if (sub == 0) { gl[ul][0]=gv[0]; gl[ul][1]=gv[1]; gl[ul][2]=gv[2]; gl[ul][3]=gv[3]; }
    __syncthreads();                               // also fences h_s for next step

    if (tid < 16) {
      float gi = gl[tid][0] + A_s[s][     tid];
      float gf = gl[tid][1] + A_s[s][16 + tid];
      float gn = gl[tid][2] + A_s[s][32 + tid];
      float go = gl[tid][3] + A_s[s][48 + tid];
      float iv = 1.0f/(1.0f + expf(-gi));
      float fv = 1.0f/(1.0f + expf(-gf));
      float gg = tanhf(gn);
      float ov = 1.0f/(1.0f + expf(-go));
      c = fv*c + iv*gg;
      float hv = ov * tanhf(c);
      if (s < 15) {
        __hip_atomic_store(&hstep[((size_t)s*BB + b)*HH + ug*16 + tid],
                           __float_as_int(hv), __ATOMIC_RELAXED,
                           __HIP_MEMORY_SCOPE_AGENT);
      } else {                                     // fold classifier
        float p = hv * clsW[ug*16 + tid];
        p += __shfl_xor(p, 1); p += __shfl_xor(p, 2);
        p += __shfl_xor(p, 4); p += __shfl_xor(p, 8);
        if (tid == 0) atomicAdd(&out[b], p + (ug == 0 ? clsb[0] : 0.0f));
      }
    }
    // no trailing barrier: next step's per-thread poll is the sync
  }
}

// ---------------------------------------------------------------------------
extern "C" void kernel_launch(void* const* d_in, const int* in_sizes, int n_in,
                              void* d_out, int out_size, void* d_ws, size_t ws_size,
                              hipStream_t stream)
{
  const float* x    = (const float*)d_in[0];
  const int*   ei   = (const int*)  d_in[1];
  const float* W1   = (const float*)d_in[2];
  const float* b1   = (const float*)d_in[3];
  const float* Wl   = (const float*)d_in[4];
  const float* Wr   = (const float*)d_in[5];
  const float* bs   = (const float*)d_in[6];
  const float* W2   = (const float*)d_in[7];
  const float* b2   = (const float*)d_in[8];
  const float* Wih  = (const float*)d_in[9];
  const float* Whh  = (const float*)d_in[10];
  const float* bih  = (const float*)d_in[11];
  const float* bhh  = (const float*)d_in[12];
  const float* clsW = (const float*)d_in[13];
  const float* clsb = (const float*)d_in[14];
  float* out = (float*)d_out;

  float* emb   = (float*)d_ws;                  // [T*B, 256]  (live through k_lstm)
  int*   hstep = (int*)(emb + (size_t)TT*BB*HH);// [15][16][256] per-step h, canary-filled

  (void)hipFuncSetAttribute(reinterpret_cast<const void*>(k_graph),
      hipFuncAttributeMaxDynamicSharedMemorySize, SM_BYTES);

  hipLaunchKernelGGL(k_graph, dim3(TT*BB), dim3(1024), SM_BYTES, stream,
                     x, ei, W1, b1, Wl, Wr, bs, W2, b2, emb);
  (void)hipMemsetAsync(hstep, 0xFF, (size_t)15*BB*HH*sizeof(int), stream);
  (void)hipMemsetAsync(out, 0, BB*sizeof(float), stream);
  hipLaunchKernelGGL(k_lstm, dim3(256), dim3(256), 0, stream,
                     emb, Wih, Whh, bih, bhh, clsW, clsb, hstep, out);
}